// Round 5
// baseline (1669.375 us; speedup 1.0000x reference)
//
#include <hip/hip_runtime.h>
#include <math.h>

#define N_NODES 8000
#define N_EDGES 64000
#define ETOT    (N_EDGES + N_NODES)   // 72000, self-loops appended
#define EDIM    16
#define NGRAPHS 64

typedef __attribute__((ext_vector_type(8))) short short8v;
typedef __attribute__((ext_vector_type(4))) short short4v;
typedef __attribute__((ext_vector_type(4))) float f32x4;

__device__ inline unsigned short f2bf(float f) {
    unsigned u = __builtin_bit_cast(unsigned, f);
    unsigned r = (u + 0x7FFF + ((u >> 16) & 1)) >> 16;   // RNE
    return (unsigned short)r;
}
__device__ inline float bf2f(unsigned short b) {
    unsigned u = ((unsigned)b) << 16;
    return __builtin_bit_cast(float, u);
}

// direct global->LDS 16B DMA (dest = uniform base + lane*16)
__device__ inline void gload16(const void* g, void* l) {
    __builtin_amdgcn_global_load_lds(
        (const __attribute__((address_space(1))) void*)g,
        (__attribute__((address_space(3))) void*)l, 16, 0, 0);
}

// ---------------- CSR build ----------------

__global__ void count_deg(const int* __restrict__ dst0, int* __restrict__ deg) {
    int e = blockIdx.x * 256 + threadIdx.x;
    if (e < N_EDGES) atomicAdd(&deg[dst0[e]], 1);
}

// efficient single-block scan: 256 threads x 32 serial + one 256 block-scan.
// emits rowptr (inclusive, +self-loop) AND woff (exclusive) in one pass.
__global__ void scan_deg2(const int* __restrict__ deg, int* __restrict__ rowptr,
                          int* __restrict__ woff) {
    __shared__ int stot[256];
    int t = threadIdx.x;
    int base = t * 32;
    int sum = 0;
    for (int j = 0; j < 32; j++) {
        int i = base + j;
        if (i < N_NODES) sum += deg[i] + 1;
    }
    stot[t] = sum;
    __syncthreads();
    for (int off = 1; off < 256; off <<= 1) {
        int u = (t >= off) ? stot[t - off] : 0;
        __syncthreads();
        stot[t] += u;
        __syncthreads();
    }
    int run = (t == 0) ? 0 : stot[t - 1];
    if (t == 0) rowptr[0] = 0;
    for (int j = 0; j < 32; j++) {
        int i = base + j;
        if (i < N_NODES) {
            int v = deg[i] + 1;
            woff[i] = run;
            rowptr[i + 1] = run + v;
            run += v;
        }
    }
}

__global__ void fill_eid(const int* __restrict__ dst0, int* __restrict__ woff,
                         int* __restrict__ eid) {
    int i = blockIdx.x * 256 + threadIdx.x;
    if (i < N_EDGES) {
        int pos = atomicAdd(&woff[dst0[i]], 1);
        eid[pos] = i;
    } else if (i < ETOT) {
        int n = i - N_EDGES;
        int pos = atomicAdd(&woff[n], 1);
        eid[pos] = i;
    }
}

__global__ void ea_loop_kernel(const int* __restrict__ rowptr, const int* __restrict__ eid,
                               const float* __restrict__ edge_attr, float* __restrict__ ea_loop) {
    int n = blockIdx.x * 256 + threadIdx.x;
    if (n >= N_NODES) return;
    float s[EDIM];
#pragma unroll
    for (int k = 0; k < EDIM; k++) s[k] = 0.f;
    int cnt = 0;
    int b = rowptr[n], t = rowptr[n + 1];
    for (int i = b; i < t; i++) {
        int e = eid[i];
        if (e < N_EDGES) {
            cnt++;
            const float* ea = edge_attr + (size_t)e * EDIM;
#pragma unroll
            for (int k = 0; k < EDIM; k++) s[k] += ea[k];
        }
    }
    float inv = 1.f / (float)(cnt > 0 ? cnt : 1);
#pragma unroll
    for (int k = 0; k < EDIM; k++) ea_loop[(size_t)n * EDIM + k] = s[k] * inv;
}

// csr_src + fp32 edge_attr in CSR order (self-loop rows = per-dst mean).
__global__ void csr_src_ea(const int* __restrict__ eid, const int* __restrict__ src0,
                           const float* __restrict__ edge_attr, const float* __restrict__ ea_loop,
                           int* __restrict__ csr_src, float* __restrict__ ea_csr) {
    int t = blockIdx.x * 256 + threadIdx.x;
    int i = t >> 2, q = t & 3;
    if (i >= ETOT) return;
    int e = eid[i];
    int s = (e < N_EDGES) ? src0[e] : (e - N_EDGES);
    if (q == 0) csr_src[i] = s;
    const float* ea = (e < N_EDGES) ? edge_attr + (size_t)e * EDIM
                                    : ea_loop + (size_t)(e - N_EDGES) * EDIM;
    *(float4*)(ea_csr + (size_t)i * 16 + q * 4) = *(const float4*)(ea + q * 4);
}

// All 4 layers' We -> fp32 WeT [ch][16] (channel-flattened across layers).
__global__ void cvt_weT(const float* __restrict__ We1, const float* __restrict__ We2,
                        const float* __restrict__ We3, const float* __restrict__ We4,
                        float* __restrict__ weT) {
    int ch = blockIdx.x * 256 + threadIdx.x;
    if (ch >= 3328) return;                  // 1536 + 1024 + 512 + 256
    const float* We; int lch, hc;
    if (ch < 1536)      { We = We1; lch = ch;        hc = 1536; }
    else if (ch < 2560) { We = We2; lch = ch - 1536; hc = 1024; }
    else if (ch < 3072) { We = We3; lch = ch - 2560; hc = 512;  }
    else                { We = We4; lch = ch - 3072; hc = 256;  }
#pragma unroll
    for (int k = 0; k < EDIM; k++)
        weT[(size_t)ch * 16 + k] = We[(size_t)k * hc + lch];
}

// ---------------- weight transpose + bf16 split, Wl & Wr in one launch (z) ----------------

__global__ __launch_bounds__(256) void cvt_wt_t2(
        const float* __restrict__ Wl, const float* __restrict__ Wr,
        short* __restrict__ WTh, short* __restrict__ WTl, int K, int Nc) {
    __shared__ float sh[32][33];
    const float* W = blockIdx.z ? Wr : Wl;
    size_t obase = blockIdx.z ? (size_t)Nc * K : 0;
    int t = threadIdx.x;
    int tx = t & 31, ty = t >> 5;            // 32 x 8
    int n0 = blockIdx.x * 32, k0 = blockIdx.y * 32;
#pragma unroll
    for (int j = 0; j < 4; j++)
        sh[ty + j * 8][tx] = W[(size_t)(k0 + ty + j * 8) * Nc + n0 + tx];
    __syncthreads();
#pragma unroll
    for (int j = 0; j < 4; j++) {
        int row = ty + j * 8;                 // local n
        float v = sh[tx][row];
        unsigned short h = f2bf(v);
        unsigned short l = f2bf(v - bf2f(h));
        size_t idx = obase + (size_t)(n0 + row) * K + k0 + tx;
        WTh[idx] = (short)h;
        WTl[idx] = (short)l;
    }
}

// ---------------- activation bf16 hi/lo pre-split (layer-1 input only) ----------------

__global__ __launch_bounds__(256) void cvt_act(
        const float* __restrict__ in, short* __restrict__ acth, short* __restrict__ actl,
        int total /* M*K, multiple of 4 */) {
    int i = blockIdx.x * 256 + threadIdx.x;
    if (i * 4 >= total) return;
    float4 v = *(const float4*)(in + (size_t)i * 4);
    unsigned short h0 = f2bf(v.x), h1 = f2bf(v.y), h2 = f2bf(v.z), h3 = f2bf(v.w);
    short4v hv = { (short)h0, (short)h1, (short)h2, (short)h3 };
    short4v lv = { (short)f2bf(v.x - bf2f(h0)), (short)f2bf(v.y - bf2f(h1)),
                   (short)f2bf(v.z - bf2f(h2)), (short)f2bf(v.w - bf2f(h3)) };
    *(short4v*)(acth + (size_t)i * 4) = hv;
    *(short4v*)(actl + (size_t)i * 4) = lv;
}

// ---------------- bf16x3 MFMA GEMM, A pre-split, fused Wl|Wr (dual bias) ----------------
// v5 (round-4 verified: FETCH 128MB = one-pass ideal, 0 bank conflicts,
// 175.6us L2-layer): single 32KB LDS buffer + T1 bijective XCD swizzle.

__global__ __launch_bounds__(256) void gemm_mfma5(
        const short* __restrict__ Ah_g, const short* __restrict__ Al_g,
        const short* __restrict__ BTh, const short* __restrict__ BTl,
        const float* __restrict__ bias1, const float* __restrict__ bias2, int hsplit,
        float* __restrict__ C, int M, int K, int Nc) {
    __shared__ __align__(16) short lds[4 * 128 * 32];   // Ah | Al | Bh | Bl, 32 KB
    int t = threadIdx.x;

    // T1: bijective XCD-chunked remap of the linear block id (m204).
    int gx = gridDim.x;
    int nwg = gx * gridDim.y;
    int orig = blockIdx.y * gx + blockIdx.x;
    int q = nwg >> 3, r = nwg & 7;
    int xcd = orig & 7, pos = orig >> 3;
    int nid = (xcd < r ? xcd * (q + 1) : r * (q + 1) + (xcd - r) * q) + pos;
    int bx = nid % gx, by = nid / gx;
    int m0 = by * 128, n0 = bx * 128;

    int lane = t & 63, wave = t >> 6;
    int wm = (wave >> 1) * 64, wn = (wave & 1) * 64;
    int fr = lane & 15, quad = lane >> 4;

    // staging: wave w owns matrix w; lane covers (row = g*16 + (lane>>2), seg = lane&3)
    int rl = lane >> 2, seg = lane & 3;
    int perm = seg ^ ((rl >> 1) & 3);                   // XOR involution
    const short* gp = (wave == 0) ? Ah_g : (wave == 1) ? Al_g : (wave == 2) ? BTh : BTl;
    int brow = (wave < 2) ? m0 : n0;
    const short* src = gp + (size_t)(brow + rl) * K + perm * 8;
    short* ldsw = &lds[wave * 4096];

    // read-side swizzled k-offset (shorts): (quad ^ ((fr>>1)&3)) * 8
    int ks = (quad ^ ((fr >> 1) & 3)) << 3;

    f32x4 acc[4][4];
#pragma unroll
    for (int i = 0; i < 4; i++)
#pragma unroll
        for (int j = 0; j < 4; j++) acc[i][j] = (f32x4)(0.f);

    for (int k0 = 0; k0 < K; k0 += 32) {
        __syncthreads();
#pragma unroll
        for (int g = 0; g < 8; g++)
            gload16(src + k0 + (size_t)g * 16 * K, ldsw + g * 512);
        __syncthreads();   // compiler drains vmcnt(0) before s_barrier

        short8v ah[4], al[4], bh[4], bl[4];
#pragma unroll
        for (int mi = 0; mi < 4; mi++) {
            int rr = (wm + mi * 16 + fr) * 32 + ks;
            ah[mi] = *(short8v*)&lds[rr];
            al[mi] = *(short8v*)&lds[4096 + rr];
        }
#pragma unroll
        for (int ni = 0; ni < 4; ni++) {
            int rr = (wn + ni * 16 + fr) * 32 + ks;
            bh[ni] = *(short8v*)&lds[8192 + rr];
            bl[ni] = *(short8v*)&lds[12288 + rr];
        }
#pragma unroll
        for (int mi = 0; mi < 4; mi++)
#pragma unroll
            for (int ni = 0; ni < 4; ni++) {
                acc[mi][ni] = __builtin_amdgcn_mfma_f32_16x16x32_bf16(
                    al[mi], bh[ni], acc[mi][ni], 0, 0, 0);
                acc[mi][ni] = __builtin_amdgcn_mfma_f32_16x16x32_bf16(
                    ah[mi], bl[ni], acc[mi][ni], 0, 0, 0);
                acc[mi][ni] = __builtin_amdgcn_mfma_f32_16x16x32_bf16(
                    ah[mi], bh[ni], acc[mi][ni], 0, 0, 0);
            }
    }

    int rbase = (lane >> 4) * 4;
#pragma unroll
    for (int ni = 0; ni < 4; ni++) {
        int col = n0 + wn + ni * 16 + fr;
        const float* bp = (col < hsplit) ? bias1 + col : bias2 + (col - hsplit);
        float bz = *bp;
#pragma unroll
        for (int mi = 0; mi < 4; mi++) {
            int row0 = m0 + wm + mi * 16 + rbase;
#pragma unroll
            for (int rr = 0; rr < 4; rr++) {
                int row = row0 + rr;
                if (row < M) C[(size_t)row * Nc + col] = acc[mi][ni][rr] + bz;
            }
        }
    }
}

// ---------------- fused GATv2 edge phase: logits + online softmax + aggregate ----------------
// One block per dst node, nthr = hc/4 threads (each owns 4 channels).
// Per edge (single pass, flash-style):
//   gather xl[src] row ONCE (coalesced hc*4B) -> ee on-the-fly from
//   register-resident WeT slice (4ch x 16 = 16 VGPR-float4) -> leakyrelu ->
//   att-dot -> wave shfl-reduce -> per-head logit (thread 0: online m/d
//   update) -> accumulate exp-weight * xlv (registers reused, no re-gather).
// xr[dst] hoisted to one load per node. Replaces edge_logits7 + aggregate5:
// cuts gather traffic ~2.9 GB -> ~1.1 GB per iter.

__global__ __launch_bounds__(384) void edge_agg(
        const int* __restrict__ rowptr, const int* __restrict__ csr_src,
        const float* __restrict__ ea_csr, const float* __restrict__ weT,
        const float* __restrict__ att, const float* __restrict__ xlr,
        const float* __restrict__ bias,
        short* __restrict__ outh, short* __restrict__ outl,
        float* __restrict__ outf, int last,
        int H, int co_shift, int hc, int stride) {
    __shared__ __align__(16) float sea[2][16];
    __shared__ float sbin[8];
    __shared__ float sm[4], sd[4], sf[4], sw[4];
    int n = blockIdx.x;
    int b = rowptr[n], t = rowptr[n + 1];
    int deg = t - b;                         // >= 1 (self-loop)
    int tid = threadIdx.x;
    int lane = tid & 63, wid = tid >> 6;
    int j0 = tid * 4;
    int h0 = j0 >> co_shift;
    int nw = (int)blockDim.x >> 6;
    int wph = nw / H;                        // waves per head (wave never straddles)

    const float* xl = xlr;
    const float* xr = xlr + hc;

    f32x4 xrv = *(const f32x4*)(xr + (size_t)n * stride + j0);
    f32x4 at4 = *(const f32x4*)(att + j0);
    f32x4 wreg[4][4];                        // WeT rows for my 4 channels
#pragma unroll
    for (int rr = 0; rr < 4; rr++)
#pragma unroll
        for (int kq = 0; kq < 4; kq++)
            wreg[rr][kq] = *(const f32x4*)(weT + (size_t)(j0 + rr) * 16 + kq * 4);

    if (tid < 4) {
        sm[tid] = -1e30f; sd[tid] = 0.f;
        *(f32x4*)&sea[0][tid * 4] = *(const f32x4*)(ea_csr + (size_t)b * 16 + tid * 4);
    }
    __syncthreads();

    int s_cur = csr_src[b];
    f32x4 xlv = *(const f32x4*)(xl + (size_t)s_cur * stride + j0);
    f32x4 acc = (f32x4)(0.f);

    for (int i = 0; i < deg; i++) {
        // prefetch next edge's xl row + stage next ea (hidden under this
        // edge's reduce chain)
        f32x4 xln = xlv;
        if (i + 1 < deg) {
            int s_nx = csr_src[b + i + 1];
            xln = *(const f32x4*)(xl + (size_t)s_nx * stride + j0);
            if (tid < 4)
                *(f32x4*)&sea[(i + 1) & 1][tid * 4] =
                    *(const f32x4*)(ea_csr + (size_t)(b + i + 1) * 16 + tid * 4);
        }

        const float* se = sea[i & 1];
        f32x4 e0 = *(const f32x4*)(se);
        f32x4 e1 = *(const f32x4*)(se + 4);
        f32x4 e2 = *(const f32x4*)(se + 8);
        f32x4 e3 = *(const f32x4*)(se + 12);
        float pd = 0.f;
#pragma unroll
        for (int rr = 0; rr < 4; rr++) {
            float ee =
                e0[0]*wreg[rr][0][0] + e0[1]*wreg[rr][0][1] + e0[2]*wreg[rr][0][2] + e0[3]*wreg[rr][0][3] +
                e1[0]*wreg[rr][1][0] + e1[1]*wreg[rr][1][1] + e1[2]*wreg[rr][1][2] + e1[3]*wreg[rr][1][3] +
                e2[0]*wreg[rr][2][0] + e2[1]*wreg[rr][2][1] + e2[2]*wreg[rr][2][2] + e2[3]*wreg[rr][2][3] +
                e3[0]*wreg[rr][3][0] + e3[1]*wreg[rr][3][1] + e3[2]*wreg[rr][3][2] + e3[3]*wreg[rr][3][3];
            float m = xlv[rr] + xrv[rr] + ee;
            float lr = (m > 0.f) ? m : 0.2f * m;
            pd += at4[rr] * lr;
        }

        // wave reduce -> per-wave bin (a wave's channels belong to ONE head)
        pd += __shfl_down(pd, 32, 64);
        pd += __shfl_down(pd, 16, 64);
        pd += __shfl_down(pd, 8, 64);
        pd += __shfl_down(pd, 4, 64);
        pd += __shfl_down(pd, 2, 64);
        pd += __shfl_down(pd, 1, 64);
        if (lane == 0) sbin[wid] = pd;
        __syncthreads();

        if (tid == 0) {
#pragma unroll
            for (int h = 0; h < 3; h++) {
                if (h >= H) break;
                float L = 0.f;
                for (int w = h * wph; w < (h + 1) * wph; w++) L += sbin[w];
                float mo = sm[h];
                float mx = fmaxf(mo, L);
                float f = expf(mo - mx);         // 0 on first edge
                float wg = expf(L - mx);
                sd[h] = sd[h] * f + wg;
                sm[h] = mx;
                sf[h] = f; sw[h] = wg;
            }
        }
        __syncthreads();

        float f = sf[h0], wg = sw[h0];
#pragma unroll
        for (int rr = 0; rr < 4; rr++)
            acc[rr] = acc[rr] * f + wg * xlv[rr];
        xlv = xln;
    }

    float inv = 1.f / sd[h0];                // self-loop guarantees > 0
    f32x4 bz = *(const f32x4*)(bias + j0);
    f32x4 o;
#pragma unroll
    for (int rr = 0; rr < 4; rr++)
        o[rr] = fmaxf(acc[rr] * inv + bz[rr], 0.f);

    if (last) {
        *(f32x4*)(outf + (size_t)n * hc + j0) = o;
    } else {
        unsigned short hx = f2bf(o[0]), hy = f2bf(o[1]), hz = f2bf(o[2]), hw = f2bf(o[3]);
        short4v hv = { (short)hx, (short)hy, (short)hz, (short)hw };
        short4v lv = { (short)f2bf(o[0] - bf2f(hx)), (short)f2bf(o[1] - bf2f(hy)),
                       (short)f2bf(o[2] - bf2f(hz)), (short)f2bf(o[3] - bf2f(hw)) };
        *(short4v*)(outh + (size_t)n * hc + j0) = hv;
        *(short4v*)(outl + (size_t)n * hc + j0) = lv;
    }
}

// ---------------- pooling + MLP head ----------------

__global__ void pool_cnt(const int* __restrict__ batch, int* __restrict__ gcnt) {
    int n = blockIdx.x * 256 + threadIdx.x;
    if (n < N_NODES) atomicAdd(&gcnt[batch[n]], 1);
}

__global__ void graph_scan(const int* __restrict__ gcnt, int* __restrict__ gstart) {
    if (threadIdx.x == 0) {
        int run = 0;
        for (int g = 0; g < NGRAPHS; g++) { gstart[g] = run; run += gcnt[g]; }
        gstart[NGRAPHS] = run;
    }
}

__global__ void pool_sum2(const int* __restrict__ gstart, const float* __restrict__ h,
                          float* __restrict__ pooled) {
    int g = blockIdx.x, qtr = blockIdx.y;
    int b = gstart[g], e = gstart[g + 1];
    int cnt = e - b;
    int lo = b + (cnt * qtr) / 4, hi = b + (cnt * (qtr + 1)) / 4;
    if (lo >= hi) return;
    int c = threadIdx.x;
    float s = 0.f;
    for (int n = lo; n < hi; n++) s += h[(size_t)n * 256 + c];
    atomicAdd(&pooled[g * 256 + c], s);
}

__global__ void mlp_head(const float* __restrict__ pooled, const int* __restrict__ gcnt,
                         const float* __restrict__ fc1w, const float* __restrict__ fc1b,
                         const float* __restrict__ fc2w, const float* __restrict__ fc2b,
                         float* __restrict__ out) {
    int g = threadIdx.x;
    if (g >= NGRAPHS) return;
    float inv = 1.f / (float)(gcnt[g] > 0 ? gcnt[g] : 1);
    float s[64];
#pragma unroll
    for (int j = 0; j < 64; j++) s[j] = fc1b[j];
    for (int c = 0; c < 256; c++) {
        float mv = pooled[g * 256 + c] * inv;
#pragma unroll
        for (int j = 0; j < 64; j++) s[j] += mv * fc1w[c * 64 + j];
    }
    float o = 0.f;
#pragma unroll
    for (int j = 0; j < 64; j++) o += fmaxf(s[j], 0.f) * fc2w[j];
    out[g] = o + fc2b[0];
}

// ---------------- launch ----------------

extern "C" void kernel_launch(void* const* d_in, const int* in_sizes, int n_in,
                              void* d_out, int out_size, void* d_ws, size_t ws_size,
                              hipStream_t stream) {
    const float* x         = (const float*)d_in[0];
    const int*   edge_index= (const int*)d_in[1];
    const float* edge_attr = (const float*)d_in[2];
    const int*   batch     = (const int*)d_in[3];
    const int* src0 = edge_index;
    const int* dst0 = edge_index + N_EDGES;

    const float *Wl[4], *bl[4], *Wr[4], *br[4], *We[4], *att[4], *bias[4];
    for (int i = 0; i < 4; i++) {
        int base = 4 + 7 * i;
        Wl[i]   = (const float*)d_in[base + 0];
        bl[i]   = (const float*)d_in[base + 1];
        Wr[i]   = (const float*)d_in[base + 2];
        br[i]   = (const float*)d_in[base + 3];
        We[i]   = (const float*)d_in[base + 4];
        att[i]  = (const float*)d_in[base + 5];
        bias[i] = (const float*)d_in[base + 6];
    }
    const float* fc1w = (const float*)d_in[32];
    const float* fc1b = (const float*)d_in[33];
    const float* fc2w = (const float*)d_in[34];
    const float* fc2b = (const float*)d_in[35];
    float* out = (float*)d_out;

    // workspace layout (float offsets); footprint unchanged (ends 56493824)
    float* ws = (float*)d_ws;
    int*   rowptr  = (int*)(ws + 0);            // 8001
    int*   woff    = (int*)(ws + 8064);         // 8000
    int*   eid     = (int*)(ws + 16128);        // 72000
    int*   csr_src = (int*)(ws + 88128);        // 72000
    float* ea_loop = ws + 232128;               // 8000*16 -> ends 360128
    float* weT     = ws + 360128;               // 3328*16 = 53248 -> ends 413376
    float* ea_csr  = ws + 470000;               // 72000*16 = 1152000 -> ends 1622000
    int*   gstart  = (int*)(ws + 1700000);      // 65 ints (< 1728128)
    float* xlr     = ws + 1728128;              // 8000*3072 (xl | xr fused, stride 2hc)
    float* hbF     = xlr + 24576000;            // final-layer fp32 out (8000*256 used)
    float* pooled  = hbF + 12288000;            // 16384
    int*   gcnt    = (int*)(pooled + 16384);    // 64 -> pad to 38608640
    short* wth     = (short*)(ws + 38608640);   // max 2*1536*1024 shorts
    short* wtl     = (short*)(ws + 40181504);   // -> ends 41754368
    short* acth    = (short*)(ws + 44107520);   // 8064*1536 shorts
    short* actl    = (short*)(ws + 50300672);   // -> ends 56493824

    hipMemsetAsync(woff, 0, N_NODES * sizeof(int), stream);
    count_deg<<<(N_EDGES + 255) / 256, 256, 0, stream>>>(dst0, woff);
    scan_deg2<<<1, 256, 0, stream>>>(woff, rowptr, woff);
    fill_eid<<<(ETOT + 255) / 256, 256, 0, stream>>>(dst0, woff, eid);
    ea_loop_kernel<<<(N_NODES + 255) / 256, 256, 0, stream>>>(rowptr, eid, edge_attr, ea_loop);
    csr_src_ea<<<(ETOT * 4 + 255) / 256, 256, 0, stream>>>(eid, src0, edge_attr, ea_loop,
                                                           csr_src, ea_csr);
    cvt_weT<<<(3328 + 255) / 256, 256, 0, stream>>>(We[0], We[1], We[2], We[3], weT);
    // layer-1 input split (later layers' splits come from edge_agg epilogue)
    cvt_act<<<(N_NODES * 256 / 4 + 255) / 256, 256, 0, stream>>>(x, acth, actl, N_NODES * 256);

    const int IN[4] = {256, 1536, 1024, 512};
    const int HH[4] = {3, 2, 2, 1};
    const int CO[4] = {512, 512, 256, 256};
    const int CS[4] = {9, 9, 8, 8};            // log2(co)
    const int CHOFF[4] = {0, 1536, 2560, 3072}; // weT channel offsets

    for (int L = 0; L < 4; L++) {
        int K = IN[L], H = HH[L], co = CO[L], hc = H * co, cs = CS[L];
        int hc2 = 2 * hc;
        dim3 gg(hc2 / 128, (N_NODES + 127) / 128);
        dim3 gw(hc / 32, K / 32, 2);
        cvt_wt_t2<<<gw, 256, 0, stream>>>(Wl[L], Wr[L], wth, wtl, K, hc);
        gemm_mfma5<<<gg, 256, 0, stream>>>(acth, actl, wth, wtl,
                                           bl[L], br[L], hc, xlr, N_NODES, K, hc2);
        int athr = hc / 4;                      // 384 / 256 / 128 / 64
        edge_agg<<<N_NODES, athr, 0, stream>>>(
            rowptr, csr_src, ea_csr, weT + (size_t)CHOFF[L] * 16,
            att[L], xlr, bias[L],
            acth, actl, hbF, (L == 3) ? 1 : 0, H, cs, hc, hc2);
    }

    hipMemsetAsync(pooled, 0, (16384 + 64) * sizeof(float), stream);
    pool_cnt<<<(N_NODES + 255) / 256, 256, 0, stream>>>(batch, gcnt);
    graph_scan<<<1, 64, 0, stream>>>(gcnt, gstart);
    dim3 gp(NGRAPHS, 4);
    pool_sum2<<<gp, 256, 0, stream>>>(gstart, hbF, pooled);
    mlp_head<<<1, 64, 0, stream>>>(pooled, gcnt, fc1w, fc1b, fc2w, fc2b, out);
}

// Round 6
// 1350.061 us; speedup vs baseline: 1.2365x; 1.2365x over previous
//
#include <hip/hip_runtime.h>
#include <math.h>

#define N_NODES 8000
#define N_EDGES 64000
#define ETOT    (N_EDGES + N_NODES)   // 72000, self-loops appended
#define EDIM    16
#define NGRAPHS 64

typedef __attribute__((ext_vector_type(8))) short short8v;
typedef __attribute__((ext_vector_type(4))) short short4v;
typedef __attribute__((ext_vector_type(4))) float f32x4;

__device__ inline unsigned short f2bf(float f) {
    unsigned u = __builtin_bit_cast(unsigned, f);
    unsigned r = (u + 0x7FFF + ((u >> 16) & 1)) >> 16;   // RNE
    return (unsigned short)r;
}
__device__ inline float bf2f(unsigned short b) {
    unsigned u = ((unsigned)b) << 16;
    return __builtin_bit_cast(float, u);
}

// direct global->LDS 16B DMA (dest = uniform base + lane*16)
__device__ inline void gload16(const void* g, void* l) {
    __builtin_amdgcn_global_load_lds(
        (const __attribute__((address_space(1))) void*)g,
        (__attribute__((address_space(3))) void*)l, 16, 0, 0);
}

// ---------------- CSR build ----------------

__global__ void count_deg(const int* __restrict__ dst0, int* __restrict__ deg) {
    int e = blockIdx.x * 256 + threadIdx.x;
    if (e < N_EDGES) atomicAdd(&deg[dst0[e]], 1);
}

// efficient single-block scan: 256 threads x 32 serial + one 256 block-scan.
// emits rowptr (inclusive, +self-loop) AND woff (exclusive) in one pass.
__global__ void scan_deg2(const int* __restrict__ deg, int* __restrict__ rowptr,
                          int* __restrict__ woff) {
    __shared__ int stot[256];
    int t = threadIdx.x;
    int base = t * 32;
    int sum = 0;
    for (int j = 0; j < 32; j++) {
        int i = base + j;
        if (i < N_NODES) sum += deg[i] + 1;
    }
    stot[t] = sum;
    __syncthreads();
    for (int off = 1; off < 256; off <<= 1) {
        int u = (t >= off) ? stot[t - off] : 0;
        __syncthreads();
        stot[t] += u;
        __syncthreads();
    }
    int run = (t == 0) ? 0 : stot[t - 1];
    if (t == 0) rowptr[0] = 0;
    for (int j = 0; j < 32; j++) {
        int i = base + j;
        if (i < N_NODES) {
            int v = deg[i] + 1;
            woff[i] = run;
            rowptr[i + 1] = run + v;
            run += v;
        }
    }
}

__global__ void fill_eid(const int* __restrict__ dst0, int* __restrict__ woff,
                         int* __restrict__ eid) {
    int i = blockIdx.x * 256 + threadIdx.x;
    if (i < N_EDGES) {
        int pos = atomicAdd(&woff[dst0[i]], 1);
        eid[pos] = i;
    } else if (i < ETOT) {
        int n = i - N_EDGES;
        int pos = atomicAdd(&woff[n], 1);
        eid[pos] = i;
    }
}

__global__ void ea_loop_kernel(const int* __restrict__ rowptr, const int* __restrict__ eid,
                               const float* __restrict__ edge_attr, float* __restrict__ ea_loop) {
    int n = blockIdx.x * 256 + threadIdx.x;
    if (n >= N_NODES) return;
    float s[EDIM];
#pragma unroll
    for (int k = 0; k < EDIM; k++) s[k] = 0.f;
    int cnt = 0;
    int b = rowptr[n], t = rowptr[n + 1];
    for (int i = b; i < t; i++) {
        int e = eid[i];
        if (e < N_EDGES) {
            cnt++;
            const float* ea = edge_attr + (size_t)e * EDIM;
#pragma unroll
            for (int k = 0; k < EDIM; k++) s[k] += ea[k];
        }
    }
    float inv = 1.f / (float)(cnt > 0 ? cnt : 1);
#pragma unroll
    for (int k = 0; k < EDIM; k++) ea_loop[(size_t)n * EDIM + k] = s[k] * inv;
}

// csr_src + fp32 edge_attr in CSR order (self-loop rows = per-dst mean).
__global__ void csr_src_ea(const int* __restrict__ eid, const int* __restrict__ src0,
                           const float* __restrict__ edge_attr, const float* __restrict__ ea_loop,
                           int* __restrict__ csr_src, float* __restrict__ ea_csr) {
    int t = blockIdx.x * 256 + threadIdx.x;
    int i = t >> 2, q = t & 3;
    if (i >= ETOT) return;
    int e = eid[i];
    int s = (e < N_EDGES) ? src0[e] : (e - N_EDGES);
    if (q == 0) csr_src[i] = s;
    const float* ea = (e < N_EDGES) ? edge_attr + (size_t)e * EDIM
                                    : ea_loop + (size_t)(e - N_EDGES) * EDIM;
    *(float4*)(ea_csr + (size_t)i * 16 + q * 4) = *(const float4*)(ea + q * 4);
}

// All 4 layers' We -> fp32 WeT [ch][16] (channel-flattened across layers).
__global__ void cvt_weT(const float* __restrict__ We1, const float* __restrict__ We2,
                        const float* __restrict__ We3, const float* __restrict__ We4,
                        float* __restrict__ weT) {
    int ch = blockIdx.x * 256 + threadIdx.x;
    if (ch >= 3328) return;                  // 1536 + 1024 + 512 + 256
    const float* We; int lch, hc;
    if (ch < 1536)      { We = We1; lch = ch;        hc = 1536; }
    else if (ch < 2560) { We = We2; lch = ch - 1536; hc = 1024; }
    else if (ch < 3072) { We = We3; lch = ch - 2560; hc = 512;  }
    else                { We = We4; lch = ch - 3072; hc = 256;  }
#pragma unroll
    for (int k = 0; k < EDIM; k++)
        weT[(size_t)ch * 16 + k] = We[(size_t)k * hc + lch];
}

// ---------------- weight transpose + bf16 split, Wl & Wr in one launch (z) ----------------

__global__ __launch_bounds__(256) void cvt_wt_t2(
        const float* __restrict__ Wl, const float* __restrict__ Wr,
        short* __restrict__ WTh, short* __restrict__ WTl, int K, int Nc) {
    __shared__ float sh[32][33];
    const float* W = blockIdx.z ? Wr : Wl;
    size_t obase = blockIdx.z ? (size_t)Nc * K : 0;
    int t = threadIdx.x;
    int tx = t & 31, ty = t >> 5;            // 32 x 8
    int n0 = blockIdx.x * 32, k0 = blockIdx.y * 32;
#pragma unroll
    for (int j = 0; j < 4; j++)
        sh[ty + j * 8][tx] = W[(size_t)(k0 + ty + j * 8) * Nc + n0 + tx];
    __syncthreads();
#pragma unroll
    for (int j = 0; j < 4; j++) {
        int row = ty + j * 8;                 // local n
        float v = sh[tx][row];
        unsigned short h = f2bf(v);
        unsigned short l = f2bf(v - bf2f(h));
        size_t idx = obase + (size_t)(n0 + row) * K + k0 + tx;
        WTh[idx] = (short)h;
        WTl[idx] = (short)l;
    }
}

// ---------------- activation bf16 hi/lo pre-split (layer-1 input only) ----------------

__global__ __launch_bounds__(256) void cvt_act(
        const float* __restrict__ in, short* __restrict__ acth, short* __restrict__ actl,
        int total /* M*K, multiple of 4 */) {
    int i = blockIdx.x * 256 + threadIdx.x;
    if (i * 4 >= total) return;
    float4 v = *(const float4*)(in + (size_t)i * 4);
    unsigned short h0 = f2bf(v.x), h1 = f2bf(v.y), h2 = f2bf(v.z), h3 = f2bf(v.w);
    short4v hv = { (short)h0, (short)h1, (short)h2, (short)h3 };
    short4v lv = { (short)f2bf(v.x - bf2f(h0)), (short)f2bf(v.y - bf2f(h1)),
                   (short)f2bf(v.z - bf2f(h2)), (short)f2bf(v.w - bf2f(h3)) };
    *(short4v*)(acth + (size_t)i * 4) = hv;
    *(short4v*)(actl + (size_t)i * 4) = lv;
}

// ---------------- bf16x3 MFMA GEMM, A pre-split, fused Wl|Wr (dual bias) ----------------
// v5 (round-4 verified: FETCH 128MB = one-pass ideal, 0 bank conflicts,
// 175.6us L2-layer): single 32KB LDS buffer + T1 bijective XCD swizzle.

__global__ __launch_bounds__(256) void gemm_mfma5(
        const short* __restrict__ Ah_g, const short* __restrict__ Al_g,
        const short* __restrict__ BTh, const short* __restrict__ BTl,
        const float* __restrict__ bias1, const float* __restrict__ bias2, int hsplit,
        float* __restrict__ C, int M, int K, int Nc) {
    __shared__ __align__(16) short lds[4 * 128 * 32];   // Ah | Al | Bh | Bl, 32 KB
    int t = threadIdx.x;

    // T1: bijective XCD-chunked remap of the linear block id (m204).
    int gx = gridDim.x;
    int nwg = gx * gridDim.y;
    int orig = blockIdx.y * gx + blockIdx.x;
    int q = nwg >> 3, r = nwg & 7;
    int xcd = orig & 7, pos = orig >> 3;
    int nid = (xcd < r ? xcd * (q + 1) : r * (q + 1) + (xcd - r) * q) + pos;
    int bx = nid % gx, by = nid / gx;
    int m0 = by * 128, n0 = bx * 128;

    int lane = t & 63, wave = t >> 6;
    int wm = (wave >> 1) * 64, wn = (wave & 1) * 64;
    int fr = lane & 15, quad = lane >> 4;

    // staging: wave w owns matrix w; lane covers (row = g*16 + (lane>>2), seg = lane&3)
    int rl = lane >> 2, seg = lane & 3;
    int perm = seg ^ ((rl >> 1) & 3);                   // XOR involution
    const short* gp = (wave == 0) ? Ah_g : (wave == 1) ? Al_g : (wave == 2) ? BTh : BTl;
    int brow = (wave < 2) ? m0 : n0;
    const short* src = gp + (size_t)(brow + rl) * K + perm * 8;
    short* ldsw = &lds[wave * 4096];

    // read-side swizzled k-offset (shorts): (quad ^ ((fr>>1)&3)) * 8
    int ks = (quad ^ ((fr >> 1) & 3)) << 3;

    f32x4 acc[4][4];
#pragma unroll
    for (int i = 0; i < 4; i++)
#pragma unroll
        for (int j = 0; j < 4; j++) acc[i][j] = (f32x4)(0.f);

    for (int k0 = 0; k0 < K; k0 += 32) {
        __syncthreads();
#pragma unroll
        for (int g = 0; g < 8; g++)
            gload16(src + k0 + (size_t)g * 16 * K, ldsw + g * 512);
        __syncthreads();   // compiler drains vmcnt(0) before s_barrier

        short8v ah[4], al[4], bh[4], bl[4];
#pragma unroll
        for (int mi = 0; mi < 4; mi++) {
            int rr = (wm + mi * 16 + fr) * 32 + ks;
            ah[mi] = *(short8v*)&lds[rr];
            al[mi] = *(short8v*)&lds[4096 + rr];
        }
#pragma unroll
        for (int ni = 0; ni < 4; ni++) {
            int rr = (wn + ni * 16 + fr) * 32 + ks;
            bh[ni] = *(short8v*)&lds[8192 + rr];
            bl[ni] = *(short8v*)&lds[12288 + rr];
        }
#pragma unroll
        for (int mi = 0; mi < 4; mi++)
#pragma unroll
            for (int ni = 0; ni < 4; ni++) {
                acc[mi][ni] = __builtin_amdgcn_mfma_f32_16x16x32_bf16(
                    al[mi], bh[ni], acc[mi][ni], 0, 0, 0);
                acc[mi][ni] = __builtin_amdgcn_mfma_f32_16x16x32_bf16(
                    ah[mi], bl[ni], acc[mi][ni], 0, 0, 0);
                acc[mi][ni] = __builtin_amdgcn_mfma_f32_16x16x32_bf16(
                    ah[mi], bh[ni], acc[mi][ni], 0, 0, 0);
            }
    }

    int rbase = (lane >> 4) * 4;
#pragma unroll
    for (int ni = 0; ni < 4; ni++) {
        int col = n0 + wn + ni * 16 + fr;
        const float* bp = (col < hsplit) ? bias1 + col : bias2 + (col - hsplit);
        float bz = *bp;
#pragma unroll
        for (int mi = 0; mi < 4; mi++) {
            int row0 = m0 + wm + mi * 16 + rbase;
#pragma unroll
            for (int rr = 0; rr < 4; rr++) {
                int row = row0 + rr;
                if (row < M) C[(size_t)row * Nc + col] = acc[mi][ni][rr] + bz;
            }
        }
    }
}

// ---------------- fused GATv2 edge phase v2: CHUNKED flash softmax+aggregate ----------------
// Round-5's per-edge sync (2 barriers + serial softmax PER EDGE) was the
// bottleneck (629us, VALU 19%, hbm 6% -> latency-bound). v2 amortizes over
// chunks of 8 edges: {stage 8 ea rows to LDS + issue 8 xl gathers} -> bar ->
// {8 partial dots + 8 shfl reduces} -> bar -> {per-HEAD-LEADER online update
// of all 8 logits: 1 rescale + 8 expf} -> bar -> {rank-1 accumulate of 8
// edges from registers}. Barriers/node ~18 -> ~6; serial expf halved; 8
// outstanding gathers. Math identical to v1 (verified absmax 0.0).

__global__ __launch_bounds__(384) void edge_agg2(
        const int* __restrict__ rowptr, const int* __restrict__ csr_src,
        const float* __restrict__ ea_csr, const float* __restrict__ weT,
        const float* __restrict__ att, const float* __restrict__ xlr,
        const float* __restrict__ bias,
        short* __restrict__ outh, short* __restrict__ outl,
        float* __restrict__ outf, int last,
        int H, int co_shift, int hc, int stride) {
    __shared__ __align__(16) float sea[8][16];
    __shared__ float sbin[6][8];             // [wave][edge] partial logit sums
    __shared__ float swg[8][4];              // per-edge per-head softmax weight
    __shared__ float sfh[4];                 // per-head rescale factor
    __shared__ float smh[4], sdh[4];         // running max / denom
    int n = blockIdx.x;
    int b = rowptr[n], t = rowptr[n + 1];
    int deg = t - b;                         // >= 1 (self-loop)
    int tid = threadIdx.x;
    int lane = tid & 63, wid = tid >> 6;
    int j0 = tid * 4;
    int h0 = j0 >> co_shift;
    int nw = (int)blockDim.x >> 6;
    int wph = nw / H;                        // waves per head (head = wph full waves)
    int tph = 1 << (co_shift - 2);           // threads per head (co/4): 128 or 64

    const float* xl = xlr;
    const float* xr = xlr + hc;

    f32x4 xrv = *(const f32x4*)(xr + (size_t)n * stride + j0);
    f32x4 at4 = *(const f32x4*)(att + j0);
    f32x4 wreg[4][4];                        // WeT rows for my 4 channels
#pragma unroll
    for (int rr = 0; rr < 4; rr++)
#pragma unroll
        for (int kq = 0; kq < 4; kq++)
            wreg[rr][kq] = *(const f32x4*)(weT + (size_t)(j0 + rr) * 16 + kq * 4);

    if (tid < 4) { smh[tid] = -1e30f; sdh[tid] = 0.f; }

    f32x4 acc = (f32x4)(0.f);

    for (int i0 = 0; i0 < deg; i0 += 8) {
        int cn = min(8, deg - i0);           // block-uniform

        // ---- stage ea rows (cn*16 <= 128 floats) ----
        for (int u = tid; u < cn * 16; u += blockDim.x)
            sea[u >> 4][u & 15] = ea_csr[(size_t)(b + i0 + (u >> 4)) * 16 + (u & 15)];

        // ---- issue all xl gathers (overlap under the barrier + compute) ----
        f32x4 xlv[8];
#pragma unroll
        for (int c = 0; c < 8; c++) {
            if (c < cn) {
                int sc = csr_src[b + i0 + c];              // block-uniform -> s_load
                xlv[c] = *(const f32x4*)(xl + (size_t)sc * stride + j0);
            } else {
                xlv[c] = (f32x4)(0.f);
            }
        }
        __syncthreads();                      // sea staged

        // ---- per-thread partial logits for the chunk ----
        float pd[8];
#pragma unroll
        for (int c = 0; c < 8; c++) {
            pd[c] = 0.f;
            if (c < cn) {
                f32x4 e0 = *(const f32x4*)&sea[c][0];
                f32x4 e1 = *(const f32x4*)&sea[c][4];
                f32x4 e2 = *(const f32x4*)&sea[c][8];
                f32x4 e3 = *(const f32x4*)&sea[c][12];
                float p = 0.f;
#pragma unroll
                for (int rr = 0; rr < 4; rr++) {
                    float ee =
                        e0[0]*wreg[rr][0][0] + e0[1]*wreg[rr][0][1] + e0[2]*wreg[rr][0][2] + e0[3]*wreg[rr][0][3] +
                        e1[0]*wreg[rr][1][0] + e1[1]*wreg[rr][1][1] + e1[2]*wreg[rr][1][2] + e1[3]*wreg[rr][1][3] +
                        e2[0]*wreg[rr][2][0] + e2[1]*wreg[rr][2][1] + e2[2]*wreg[rr][2][2] + e2[3]*wreg[rr][2][3] +
                        e3[0]*wreg[rr][3][0] + e3[1]*wreg[rr][3][1] + e3[2]*wreg[rr][3][2] + e3[3]*wreg[rr][3][3];
                    float m = xlv[c][rr] + xrv[rr] + ee;
                    float lr = (m > 0.f) ? m : 0.2f * m;
                    p += at4[rr] * lr;
                }
                pd[c] = p;
            }
        }

        // ---- wave reduce each edge (cn uniform -> no divergence) ----
#pragma unroll
        for (int c = 0; c < 8; c++) {
            if (c < cn) {
                float p = pd[c];
                p += __shfl_down(p, 32, 64);
                p += __shfl_down(p, 16, 64);
                p += __shfl_down(p, 8, 64);
                p += __shfl_down(p, 4, 64);
                p += __shfl_down(p, 2, 64);
                p += __shfl_down(p, 1, 64);
                if (lane == 0) sbin[wid][c] = p;
            }
        }
        __syncthreads();                      // sbin ready

        // ---- per-head leader: online update of 8 logits at once ----
        if ((tid & (tph - 1)) == 0) {
            int h = h0;
            float mo = smh[h];
            float L[8];
            float mx = mo;
#pragma unroll
            for (int c = 0; c < 8; c++) {
                if (c < cn) {
                    float s = 0.f;
                    for (int w = h * wph; w < (h + 1) * wph; w++) s += sbin[w][c];
                    L[c] = s;
                    mx = fmaxf(mx, s);
                }
            }
            float f = expf(mo - mx);          // 0 on first chunk (mo = -1e30)
            float d = sdh[h] * f;
#pragma unroll
            for (int c = 0; c < 8; c++) {
                if (c < cn) {
                    float wg = expf(L[c] - mx);
                    swg[c][h] = wg;
                    d += wg;
                }
            }
            smh[h] = mx; sdh[h] = d; sfh[h] = f;
        }
        __syncthreads();                      // swg/sfh ready

        // ---- rank-1 accumulate from registers ----
        float f = sfh[h0];
#pragma unroll
        for (int rr = 0; rr < 4; rr++) acc[rr] *= f;
#pragma unroll
        for (int c = 0; c < 8; c++) {
            if (c < cn) {
                float wg = swg[c][h0];
#pragma unroll
                for (int rr = 0; rr < 4; rr++)
                    acc[rr] += wg * xlv[c][rr];
            }
        }
    }

    float inv = 1.f / sdh[h0];               // self-loop guarantees > 0
    f32x4 bz = *(const f32x4*)(bias + j0);
    f32x4 o;
#pragma unroll
    for (int rr = 0; rr < 4; rr++)
        o[rr] = fmaxf(acc[rr] * inv + bz[rr], 0.f);

    if (last) {
        *(f32x4*)(outf + (size_t)n * hc + j0) = o;
    } else {
        unsigned short hx = f2bf(o[0]), hy = f2bf(o[1]), hz = f2bf(o[2]), hw = f2bf(o[3]);
        short4v hv = { (short)hx, (short)hy, (short)hz, (short)hw };
        short4v lv = { (short)f2bf(o[0] - bf2f(hx)), (short)f2bf(o[1] - bf2f(hy)),
                       (short)f2bf(o[2] - bf2f(hz)), (short)f2bf(o[3] - bf2f(hw)) };
        *(short4v*)(outh + (size_t)n * hc + j0) = hv;
        *(short4v*)(outl + (size_t)n * hc + j0) = lv;
    }
}

// ---------------- pooling + MLP head ----------------

__global__ void pool_cnt(const int* __restrict__ batch, int* __restrict__ gcnt) {
    int n = blockIdx.x * 256 + threadIdx.x;
    if (n < N_NODES) atomicAdd(&gcnt[batch[n]], 1);
}

__global__ void graph_scan(const int* __restrict__ gcnt, int* __restrict__ gstart) {
    if (threadIdx.x == 0) {
        int run = 0;
        for (int g = 0; g < NGRAPHS; g++) { gstart[g] = run; run += gcnt[g]; }
        gstart[NGRAPHS] = run;
    }
}

__global__ void pool_sum2(const int* __restrict__ gstart, const float* __restrict__ h,
                          float* __restrict__ pooled) {
    int g = blockIdx.x, qtr = blockIdx.y;
    int b = gstart[g], e = gstart[g + 1];
    int cnt = e - b;
    int lo = b + (cnt * qtr) / 4, hi = b + (cnt * (qtr + 1)) / 4;
    if (lo >= hi) return;
    int c = threadIdx.x;
    float s = 0.f;
    for (int n = lo; n < hi; n++) s += h[(size_t)n * 256 + c];
    atomicAdd(&pooled[g * 256 + c], s);
}

__global__ void mlp_head(const float* __restrict__ pooled, const int* __restrict__ gcnt,
                         const float* __restrict__ fc1w, const float* __restrict__ fc1b,
                         const float* __restrict__ fc2w, const float* __restrict__ fc2b,
                         float* __restrict__ out) {
    int g = threadIdx.x;
    if (g >= NGRAPHS) return;
    float inv = 1.f / (float)(gcnt[g] > 0 ? gcnt[g] : 1);
    float s[64];
#pragma unroll
    for (int j = 0; j < 64; j++) s[j] = fc1b[j];
    for (int c = 0; c < 256; c++) {
        float mv = pooled[g * 256 + c] * inv;
#pragma unroll
        for (int j = 0; j < 64; j++) s[j] += mv * fc1w[c * 64 + j];
    }
    float o = 0.f;
#pragma unroll
    for (int j = 0; j < 64; j++) o += fmaxf(s[j], 0.f) * fc2w[j];
    out[g] = o + fc2b[0];
}

// ---------------- launch ----------------

extern "C" void kernel_launch(void* const* d_in, const int* in_sizes, int n_in,
                              void* d_out, int out_size, void* d_ws, size_t ws_size,
                              hipStream_t stream) {
    const float* x         = (const float*)d_in[0];
    const int*   edge_index= (const int*)d_in[1];
    const float* edge_attr = (const float*)d_in[2];
    const int*   batch     = (const int*)d_in[3];
    const int* src0 = edge_index;
    const int* dst0 = edge_index + N_EDGES;

    const float *Wl[4], *bl[4], *Wr[4], *br[4], *We[4], *att[4], *bias[4];
    for (int i = 0; i < 4; i++) {
        int base = 4 + 7 * i;
        Wl[i]   = (const float*)d_in[base + 0];
        bl[i]   = (const float*)d_in[base + 1];
        Wr[i]   = (const float*)d_in[base + 2];
        br[i]   = (const float*)d_in[base + 3];
        We[i]   = (const float*)d_in[base + 4];
        att[i]  = (const float*)d_in[base + 5];
        bias[i] = (const float*)d_in[base + 6];
    }
    const float* fc1w = (const float*)d_in[32];
    const float* fc1b = (const float*)d_in[33];
    const float* fc2w = (const float*)d_in[34];
    const float* fc2b = (const float*)d_in[35];
    float* out = (float*)d_out;

    // workspace layout (float offsets); footprint unchanged (ends 56493824)
    float* ws = (float*)d_ws;
    int*   rowptr  = (int*)(ws + 0);            // 8001
    int*   woff    = (int*)(ws + 8064);         // 8000
    int*   eid     = (int*)(ws + 16128);        // 72000
    int*   csr_src = (int*)(ws + 88128);        // 72000
    float* ea_loop = ws + 232128;               // 8000*16 -> ends 360128
    float* weT     = ws + 360128;               // 3328*16 = 53248 -> ends 413376
    float* ea_csr  = ws + 470000;               // 72000*16 = 1152000 -> ends 1622000
    int*   gstart  = (int*)(ws + 1700000);      // 65 ints (< 1728128)
    float* xlr     = ws + 1728128;              // 8000*3072 (xl | xr fused, stride 2hc)
    float* hbF     = xlr + 24576000;            // final-layer fp32 out (8000*256 used)
    float* pooled  = hbF + 12288000;            // 16384
    int*   gcnt    = (int*)(pooled + 16384);    // 64 -> pad to 38608640
    short* wth     = (short*)(ws + 38608640);   // max 2*1536*1024 shorts
    short* wtl     = (short*)(ws + 40181504);   // -> ends 41754368
    short* acth    = (short*)(ws + 44107520);   // 8064*1536 shorts
    short* actl    = (short*)(ws + 50300672);   // -> ends 56493824

    hipMemsetAsync(woff, 0, N_NODES * sizeof(int), stream);
    count_deg<<<(N_EDGES + 255) / 256, 256, 0, stream>>>(dst0, woff);
    scan_deg2<<<1, 256, 0, stream>>>(woff, rowptr, woff);
    fill_eid<<<(ETOT + 255) / 256, 256, 0, stream>>>(dst0, woff, eid);
    ea_loop_kernel<<<(N_NODES + 255) / 256, 256, 0, stream>>>(rowptr, eid, edge_attr, ea_loop);
    csr_src_ea<<<(ETOT * 4 + 255) / 256, 256, 0, stream>>>(eid, src0, edge_attr, ea_loop,
                                                           csr_src, ea_csr);
    cvt_weT<<<(3328 + 255) / 256, 256, 0, stream>>>(We[0], We[1], We[2], We[3], weT);
    // layer-1 input split (later layers' splits come from edge_agg2 epilogue)
    cvt_act<<<(N_NODES * 256 / 4 + 255) / 256, 256, 0, stream>>>(x, acth, actl, N_NODES * 256);

    const int IN[4] = {256, 1536, 1024, 512};
    const int HH[4] = {3, 2, 2, 1};
    const int CO[4] = {512, 512, 256, 256};
    const int CS[4] = {9, 9, 8, 8};            // log2(co)
    const int CHOFF[4] = {0, 1536, 2560, 3072}; // weT channel offsets

    for (int L = 0; L < 4; L++) {
        int K = IN[L], H = HH[L], co = CO[L], hc = H * co, cs = CS[L];
        int hc2 = 2 * hc;
        dim3 gg(hc2 / 128, (N_NODES + 127) / 128);
        dim3 gw(hc / 32, K / 32, 2);
        cvt_wt_t2<<<gw, 256, 0, stream>>>(Wl[L], Wr[L], wth, wtl, K, hc);
        gemm_mfma5<<<gg, 256, 0, stream>>>(acth, actl, wth, wtl,
                                           bl[L], br[L], hc, xlr, N_NODES, K, hc2);
        int athr = hc / 4;                      // 384 / 256 / 128 / 64
        edge_agg2<<<N_NODES, athr, 0, stream>>>(
            rowptr, csr_src, ea_csr, weT + (size_t)CHOFF[L] * 16,
            att[L], xlr, bias[L],
            acth, actl, hbF, (L == 3) ? 1 : 0, H, cs, hc, hc2);
    }

    hipMemsetAsync(pooled, 0, (16384 + 64) * sizeof(float), stream);
    pool_cnt<<<(N_NODES + 255) / 256, 256, 0, stream>>>(batch, gcnt);
    graph_scan<<<1, 64, 0, stream>>>(gcnt, gstart);
    dim3 gp(NGRAPHS, 4);
    pool_sum2<<<gp, 256, 0, stream>>>(gstart, hbF, pooled);
    mlp_head<<<1, 64, 0, stream>>>(pooled, gcnt, fc1w, fc1b, fc2w, fc2b, out);
}

// Round 7
// 1251.319 us; speedup vs baseline: 1.3341x; 1.0789x over previous
//
#include <hip/hip_runtime.h>
#include <math.h>

#define N_NODES 8000
#define N_EDGES 64000
#define ETOT    (N_EDGES + N_NODES)   // 72000, self-loops appended
#define EDIM    16
#define NGRAPHS 64

typedef __attribute__((ext_vector_type(8))) short short8v;
typedef __attribute__((ext_vector_type(4))) short short4v;
typedef __attribute__((ext_vector_type(4))) float f32x4;

__device__ inline unsigned short f2bf(float f) {
    unsigned u = __builtin_bit_cast(unsigned, f);
    unsigned r = (u + 0x7FFF + ((u >> 16) & 1)) >> 16;   // RNE
    return (unsigned short)r;
}
__device__ inline float bf2f(unsigned short b) {
    unsigned u = ((unsigned)b) << 16;
    return __builtin_bit_cast(float, u);
}

// direct global->LDS 16B DMA (dest = uniform base + lane*16)
__device__ inline void gload16(const void* g, void* l) {
    __builtin_amdgcn_global_load_lds(
        (const __attribute__((address_space(1))) void*)g,
        (__attribute__((address_space(3))) void*)l, 16, 0, 0);
}

// ---------------- CSR build ----------------

__global__ void count_deg(const int* __restrict__ dst0, int* __restrict__ deg) {
    int e = blockIdx.x * 256 + threadIdx.x;
    if (e < N_EDGES) atomicAdd(&deg[dst0[e]], 1);
}

// efficient single-block scan: 256 threads x 32 serial + one 256 block-scan.
// emits rowptr (inclusive, +self-loop) AND woff (exclusive) in one pass.
__global__ void scan_deg2(const int* __restrict__ deg, int* __restrict__ rowptr,
                          int* __restrict__ woff) {
    __shared__ int stot[256];
    int t = threadIdx.x;
    int base = t * 32;
    int sum = 0;
    for (int j = 0; j < 32; j++) {
        int i = base + j;
        if (i < N_NODES) sum += deg[i] + 1;
    }
    stot[t] = sum;
    __syncthreads();
    for (int off = 1; off < 256; off <<= 1) {
        int u = (t >= off) ? stot[t - off] : 0;
        __syncthreads();
        stot[t] += u;
        __syncthreads();
    }
    int run = (t == 0) ? 0 : stot[t - 1];
    if (t == 0) rowptr[0] = 0;
    for (int j = 0; j < 32; j++) {
        int i = base + j;
        if (i < N_NODES) {
            int v = deg[i] + 1;
            woff[i] = run;
            rowptr[i + 1] = run + v;
            run += v;
        }
    }
}

__global__ void fill_eid(const int* __restrict__ dst0, int* __restrict__ woff,
                         int* __restrict__ eid) {
    int i = blockIdx.x * 256 + threadIdx.x;
    if (i < N_EDGES) {
        int pos = atomicAdd(&woff[dst0[i]], 1);
        eid[pos] = i;
    } else if (i < ETOT) {
        int n = i - N_EDGES;
        int pos = atomicAdd(&woff[n], 1);
        eid[pos] = i;
    }
}

__global__ void csr_fill_dst(const int* __restrict__ rowptr, int* __restrict__ csr_dst) {
    int n = blockIdx.x * 256 + threadIdx.x;
    if (n >= N_NODES) return;
    int b = rowptr[n], t = rowptr[n + 1];
    for (int i = b; i < t; i++) csr_dst[i] = n;
}

__global__ void ea_loop_kernel(const int* __restrict__ rowptr, const int* __restrict__ eid,
                               const float* __restrict__ edge_attr, float* __restrict__ ea_loop) {
    int n = blockIdx.x * 256 + threadIdx.x;
    if (n >= N_NODES) return;
    float s[EDIM];
#pragma unroll
    for (int k = 0; k < EDIM; k++) s[k] = 0.f;
    int cnt = 0;
    int b = rowptr[n], t = rowptr[n + 1];
    for (int i = b; i < t; i++) {
        int e = eid[i];
        if (e < N_EDGES) {
            cnt++;
            const float* ea = edge_attr + (size_t)e * EDIM;
#pragma unroll
            for (int k = 0; k < EDIM; k++) s[k] += ea[k];
        }
    }
    float inv = 1.f / (float)(cnt > 0 ? cnt : 1);
#pragma unroll
    for (int k = 0; k < EDIM; k++) ea_loop[(size_t)n * EDIM + k] = s[k] * inv;
}

// csr_src + fp32 edge_attr in CSR order (self-loop rows = per-dst mean).
__global__ void csr_src_ea(const int* __restrict__ eid, const int* __restrict__ src0,
                           const float* __restrict__ edge_attr, const float* __restrict__ ea_loop,
                           int* __restrict__ csr_src, float* __restrict__ ea_csr) {
    int t = blockIdx.x * 256 + threadIdx.x;
    int i = t >> 2, q = t & 3;
    if (i >= ETOT) return;
    int e = eid[i];
    int s = (e < N_EDGES) ? src0[e] : (e - N_EDGES);
    if (q == 0) csr_src[i] = s;
    const float* ea = (e < N_EDGES) ? edge_attr + (size_t)e * EDIM
                                    : ea_loop + (size_t)(e - N_EDGES) * EDIM;
    *(float4*)(ea_csr + (size_t)i * 16 + q * 4) = *(const float4*)(ea + q * 4);
}

// All 4 layers' We -> fp32 WeT [ch][16] (channel-flattened across layers).
__global__ void cvt_weT(const float* __restrict__ We1, const float* __restrict__ We2,
                        const float* __restrict__ We3, const float* __restrict__ We4,
                        float* __restrict__ weT) {
    int ch = blockIdx.x * 256 + threadIdx.x;
    if (ch >= 3328) return;                  // 1536 + 1024 + 512 + 256
    const float* We; int lch, hc;
    if (ch < 1536)      { We = We1; lch = ch;        hc = 1536; }
    else if (ch < 2560) { We = We2; lch = ch - 1536; hc = 1024; }
    else if (ch < 3072) { We = We3; lch = ch - 2560; hc = 512;  }
    else                { We = We4; lch = ch - 3072; hc = 256;  }
#pragma unroll
    for (int k = 0; k < EDIM; k++)
        weT[(size_t)ch * 16 + k] = We[(size_t)k * hc + lch];
}

// ---------------- weight transpose + bf16 split, Wl & Wr in one launch (z) ----------------

__global__ __launch_bounds__(256) void cvt_wt_t2(
        const float* __restrict__ Wl, const float* __restrict__ Wr,
        short* __restrict__ WTh, short* __restrict__ WTl, int K, int Nc) {
    __shared__ float sh[32][33];
    const float* W = blockIdx.z ? Wr : Wl;
    size_t obase = blockIdx.z ? (size_t)Nc * K : 0;
    int t = threadIdx.x;
    int tx = t & 31, ty = t >> 5;            // 32 x 8
    int n0 = blockIdx.x * 32, k0 = blockIdx.y * 32;
#pragma unroll
    for (int j = 0; j < 4; j++)
        sh[ty + j * 8][tx] = W[(size_t)(k0 + ty + j * 8) * Nc + n0 + tx];
    __syncthreads();
#pragma unroll
    for (int j = 0; j < 4; j++) {
        int row = ty + j * 8;                 // local n
        float v = sh[tx][row];
        unsigned short h = f2bf(v);
        unsigned short l = f2bf(v - bf2f(h));
        size_t idx = obase + (size_t)(n0 + row) * K + k0 + tx;
        WTh[idx] = (short)h;
        WTl[idx] = (short)l;
    }
}

// ---------------- activation bf16 hi/lo pre-split (layer-1 input only) ----------------

__global__ __launch_bounds__(256) void cvt_act(
        const float* __restrict__ in, short* __restrict__ acth, short* __restrict__ actl,
        int total /* M*K, multiple of 4 */) {
    int i = blockIdx.x * 256 + threadIdx.x;
    if (i * 4 >= total) return;
    float4 v = *(const float4*)(in + (size_t)i * 4);
    unsigned short h0 = f2bf(v.x), h1 = f2bf(v.y), h2 = f2bf(v.z), h3 = f2bf(v.w);
    short4v hv = { (short)h0, (short)h1, (short)h2, (short)h3 };
    short4v lv = { (short)f2bf(v.x - bf2f(h0)), (short)f2bf(v.y - bf2f(h1)),
                   (short)f2bf(v.z - bf2f(h2)), (short)f2bf(v.w - bf2f(h3)) };
    *(short4v*)(acth + (size_t)i * 4) = hv;
    *(short4v*)(actl + (size_t)i * 4) = lv;
}

// ---------------- bf16x3 MFMA GEMM, A pre-split, fused Wl|Wr (dual bias) ----------------
// v5 (round-4 verified: FETCH 128MB = one-pass ideal, 0 bank conflicts,
// 175.6us L2-layer): single 32KB LDS buffer + T1 bijective XCD swizzle.

__global__ __launch_bounds__(256) void gemm_mfma5(
        const short* __restrict__ Ah_g, const short* __restrict__ Al_g,
        const short* __restrict__ BTh, const short* __restrict__ BTl,
        const float* __restrict__ bias1, const float* __restrict__ bias2, int hsplit,
        float* __restrict__ C, int M, int K, int Nc) {
    __shared__ __align__(16) short lds[4 * 128 * 32];   // Ah | Al | Bh | Bl, 32 KB
    int t = threadIdx.x;

    // T1: bijective XCD-chunked remap of the linear block id (m204).
    int gx = gridDim.x;
    int nwg = gx * gridDim.y;
    int orig = blockIdx.y * gx + blockIdx.x;
    int q = nwg >> 3, r = nwg & 7;
    int xcd = orig & 7, pos = orig >> 3;
    int nid = (xcd < r ? xcd * (q + 1) : r * (q + 1) + (xcd - r) * q) + pos;
    int bx = nid % gx, by = nid / gx;
    int m0 = by * 128, n0 = bx * 128;

    int lane = t & 63, wave = t >> 6;
    int wm = (wave >> 1) * 64, wn = (wave & 1) * 64;
    int fr = lane & 15, quad = lane >> 4;

    // staging: wave w owns matrix w; lane covers (row = g*16 + (lane>>2), seg = lane&3)
    int rl = lane >> 2, seg = lane & 3;
    int perm = seg ^ ((rl >> 1) & 3);                   // XOR involution
    const short* gp = (wave == 0) ? Ah_g : (wave == 1) ? Al_g : (wave == 2) ? BTh : BTl;
    int brow = (wave < 2) ? m0 : n0;
    const short* src = gp + (size_t)(brow + rl) * K + perm * 8;
    short* ldsw = &lds[wave * 4096];

    // read-side swizzled k-offset (shorts): (quad ^ ((fr>>1)&3)) * 8
    int ks = (quad ^ ((fr >> 1) & 3)) << 3;

    f32x4 acc[4][4];
#pragma unroll
    for (int i = 0; i < 4; i++)
#pragma unroll
        for (int j = 0; j < 4; j++) acc[i][j] = (f32x4)(0.f);

    for (int k0 = 0; k0 < K; k0 += 32) {
        __syncthreads();
#pragma unroll
        for (int g = 0; g < 8; g++)
            gload16(src + k0 + (size_t)g * 16 * K, ldsw + g * 512);
        __syncthreads();   // compiler drains vmcnt(0) before s_barrier

        short8v ah[4], al[4], bh[4], bl[4];
#pragma unroll
        for (int mi = 0; mi < 4; mi++) {
            int rr = (wm + mi * 16 + fr) * 32 + ks;
            ah[mi] = *(short8v*)&lds[rr];
            al[mi] = *(short8v*)&lds[4096 + rr];
        }
#pragma unroll
        for (int ni = 0; ni < 4; ni++) {
            int rr = (wn + ni * 16 + fr) * 32 + ks;
            bh[ni] = *(short8v*)&lds[8192 + rr];
            bl[ni] = *(short8v*)&lds[12288 + rr];
        }
#pragma unroll
        for (int mi = 0; mi < 4; mi++)
#pragma unroll
            for (int ni = 0; ni < 4; ni++) {
                acc[mi][ni] = __builtin_amdgcn_mfma_f32_16x16x32_bf16(
                    al[mi], bh[ni], acc[mi][ni], 0, 0, 0);
                acc[mi][ni] = __builtin_amdgcn_mfma_f32_16x16x32_bf16(
                    ah[mi], bl[ni], acc[mi][ni], 0, 0, 0);
                acc[mi][ni] = __builtin_amdgcn_mfma_f32_16x16x32_bf16(
                    ah[mi], bh[ni], acc[mi][ni], 0, 0, 0);
            }
    }

    int rbase = (lane >> 4) * 4;
#pragma unroll
    for (int ni = 0; ni < 4; ni++) {
        int col = n0 + wn + ni * 16 + fr;
        const float* bp = (col < hsplit) ? bias1 + col : bias2 + (col - hsplit);
        float bz = *bp;
#pragma unroll
        for (int mi = 0; mi < 4; mi++) {
            int row0 = m0 + wm + mi * 16 + rbase;
#pragma unroll
            for (int rr = 0; rr < 4; rr++) {
                int row = row0 + rr;
                if (row < M) C[(size_t)row * Nc + col] = acc[mi][ni][rr] + bz;
            }
        }
    }
}

// ---------------- edge logits v8: wave-per-edge coalesced partial logits ----------------
// Two-pass pipeline restored (fused v1/v2 refuted: per-node serialization cost
// > traffic saving). v8 replaces edge_logits7's 16-rows-x-64B scattered gather
// with one WAVE per edge: 64 lanes read 64x16B CONSECUTIVE (lane = channel
// quad) = one 1KB contiguous request. s/d/ea are wave-uniform -> scalar loads.
// Each block covers a 256-channel slice; logit = sum_ch att*lrelu(m_ch)
// decomposes across slices, so slices atomicAdd partial logits (<=2 adders
// per logit, memset first). No LDS, no barriers. ee is fp32 (validated R5/R6).

__global__ __launch_bounds__(256) void edge_logits8(
        const int* __restrict__ csr_src, const int* __restrict__ csr_dst,
        const float* __restrict__ ea_csr, const float* __restrict__ weT,
        const float* __restrict__ att, const float* __restrict__ xlr,
        float* __restrict__ logits, int H, int co_shift, int hc, int stride) {
    int tid = threadIdx.x;
    int lane = tid & 63, wave = tid >> 6;
    int sl = blockIdx.y;                     // 256-channel slice (within one head)
    int head = (sl << 8) >> co_shift;
    int cb = (sl << 8) + lane * 4;           // this lane's channel base
    int e0 = blockIdx.x * 64 + wave * 16;    // ETOT % 64 == 0

    const float* xl = xlr;
    const float* xr = xlr + hc;

    f32x4 at4 = *(const f32x4*)(att + cb);
    f32x4 wreg[4][4];                        // WeT rows for my 4 channels
#pragma unroll
    for (int rr = 0; rr < 4; rr++)
#pragma unroll
        for (int kq = 0; kq < 4; kq++)
            wreg[rr][kq] = *(const f32x4*)(weT + (size_t)(cb + rr) * 16 + kq * 4);

#pragma unroll 4
    for (int c = 0; c < 16; c++) {
        int e = e0 + c;
        int s = csr_src[e], d = csr_dst[e];  // wave-uniform -> SGPR
        const float* ea = ea_csr + (size_t)e * 16;
        f32x4 e0v = *(const f32x4*)(ea);
        f32x4 e1v = *(const f32x4*)(ea + 4);
        f32x4 e2v = *(const f32x4*)(ea + 8);
        f32x4 e3v = *(const f32x4*)(ea + 12);
        f32x4 xlv = *(const f32x4*)(xl + (size_t)s * stride + cb);
        f32x4 xrv = *(const f32x4*)(xr + (size_t)d * stride + cb);
        float p = 0.f;
#pragma unroll
        for (int rr = 0; rr < 4; rr++) {
            float ee =
                e0v[0]*wreg[rr][0][0] + e0v[1]*wreg[rr][0][1] + e0v[2]*wreg[rr][0][2] + e0v[3]*wreg[rr][0][3] +
                e1v[0]*wreg[rr][1][0] + e1v[1]*wreg[rr][1][1] + e1v[2]*wreg[rr][1][2] + e1v[3]*wreg[rr][1][3] +
                e2v[0]*wreg[rr][2][0] + e2v[1]*wreg[rr][2][1] + e2v[2]*wreg[rr][2][2] + e2v[3]*wreg[rr][2][3] +
                e3v[0]*wreg[rr][3][0] + e3v[1]*wreg[rr][3][1] + e3v[2]*wreg[rr][3][2] + e3v[3]*wreg[rr][3][3];
            float m = xlv[rr] + xrv[rr] + ee;
            float lr = (m > 0.f) ? m : 0.2f * m;
            p += at4[rr] * lr;
        }
        p += __shfl_down(p, 32, 64);
        p += __shfl_down(p, 16, 64);
        p += __shfl_down(p, 8, 64);
        p += __shfl_down(p, 4, 64);
        p += __shfl_down(p, 2, 64);
        p += __shfl_down(p, 1, 64);
        if (lane == 0)
            atomicAdd(&logits[(size_t)e * H + head], p);
    }
}

// ---------------- fused softmax + aggregation v5 (round-4 proven): bf16 epilogue ----------------

__global__ __launch_bounds__(256) void aggregate5(
        const int* __restrict__ rowptr, const int* __restrict__ csr_src,
        const float* __restrict__ logits, const float* __restrict__ xl,
        const float* __restrict__ bias,
        short* __restrict__ outh, short* __restrict__ outl,
        float* __restrict__ outf, int last,
        int H, int co_shift, int hc, int stride) {
    __shared__ int ssrc[64];
    __shared__ float salp[64][4];
    __shared__ float sm[4], sinv[4];
    int n = blockIdx.x;
    int b = rowptr[n], t = rowptr[n + 1];
    int tid = threadIdx.x;
    int nthr = blockDim.x;

    if (tid < H) {
        float m = -1e30f;
        for (int i = b; i < t; i++)
            m = fmaxf(m, logits[(size_t)i * H + tid]);
        float s = 0.f;
        for (int i = b; i < t; i++)
            s += expf(logits[(size_t)i * H + tid] - m);
        sm[tid] = m;
        sinv[tid] = 1.f / s;    // self-loop guarantees s > 0
    }
    __syncthreads();

    int j0 = tid * 4;
    int j1 = j0 + nthr * 4;
    int h0 = j0 >> co_shift;
    int h1 = j1 >> co_shift;
    bool act1 = j1 < hc;

    float4 acc0 = make_float4(0.f, 0.f, 0.f, 0.f);
    float4 acc1 = make_float4(0.f, 0.f, 0.f, 0.f);

    for (int cb = b; cb < t; cb += 64) {
        int m = min(64, t - cb);
        __syncthreads();
        for (int i = tid; i < m; i += nthr) {
            ssrc[i] = csr_src[cb + i];
            for (int h = 0; h < H; h++)
                salp[i][h] = expf(logits[(size_t)(cb + i) * H + h] - sm[h]) * sinv[h];
        }
        __syncthreads();
        for (int i = 0; i < m; i++) {
            int s = ssrc[i];
            const float* base = xl + (size_t)s * stride;
            {
                float a = salp[i][h0];
                float4 v = *(const float4*)(base + j0);
                acc0.x += a * v.x; acc0.y += a * v.y;
                acc0.z += a * v.z; acc0.w += a * v.w;
            }
            if (act1) {
                float a = salp[i][h1];
                float4 v = *(const float4*)(base + j1);
                acc1.x += a * v.x; acc1.y += a * v.y;
                acc1.z += a * v.z; acc1.w += a * v.w;
            }
        }
    }

    float4 bz0 = *(const float4*)(bias + j0);
    float4 o0;
    o0.x = fmaxf(acc0.x + bz0.x, 0.f); o0.y = fmaxf(acc0.y + bz0.y, 0.f);
    o0.z = fmaxf(acc0.z + bz0.z, 0.f); o0.w = fmaxf(acc0.w + bz0.w, 0.f);
    if (last) {
        *(float4*)(outf + (size_t)n * hc + j0) = o0;
    } else {
        unsigned short hx = f2bf(o0.x), hy = f2bf(o0.y), hz = f2bf(o0.z), hw = f2bf(o0.w);
        short4v hv = { (short)hx, (short)hy, (short)hz, (short)hw };
        short4v lv = { (short)f2bf(o0.x - bf2f(hx)), (short)f2bf(o0.y - bf2f(hy)),
                       (short)f2bf(o0.z - bf2f(hz)), (short)f2bf(o0.w - bf2f(hw)) };
        *(short4v*)(outh + (size_t)n * hc + j0) = hv;
        *(short4v*)(outl + (size_t)n * hc + j0) = lv;
    }
    if (act1) {
        float4 bz1 = *(const float4*)(bias + j1);
        float4 o1;
        o1.x = fmaxf(acc1.x + bz1.x, 0.f); o1.y = fmaxf(acc1.y + bz1.y, 0.f);
        o1.z = fmaxf(acc1.z + bz1.z, 0.f); o1.w = fmaxf(acc1.w + bz1.w, 0.f);
        if (last) {
            *(float4*)(outf + (size_t)n * hc + j1) = o1;
        } else {
            unsigned short hx = f2bf(o1.x), hy = f2bf(o1.y), hz = f2bf(o1.z), hw = f2bf(o1.w);
            short4v hv = { (short)hx, (short)hy, (short)hz, (short)hw };
            short4v lv = { (short)f2bf(o1.x - bf2f(hx)), (short)f2bf(o1.y - bf2f(hy)),
                           (short)f2bf(o1.z - bf2f(hz)), (short)f2bf(o1.w - bf2f(hw)) };
            *(short4v*)(outh + (size_t)n * hc + j1) = hv;
            *(short4v*)(outl + (size_t)n * hc + j1) = lv;
        }
    }
}

// ---------------- pooling + MLP head ----------------

__global__ void pool_cnt(const int* __restrict__ batch, int* __restrict__ gcnt) {
    int n = blockIdx.x * 256 + threadIdx.x;
    if (n < N_NODES) atomicAdd(&gcnt[batch[n]], 1);
}

__global__ void graph_scan(const int* __restrict__ gcnt, int* __restrict__ gstart) {
    if (threadIdx.x == 0) {
        int run = 0;
        for (int g = 0; g < NGRAPHS; g++) { gstart[g] = run; run += gcnt[g]; }
        gstart[NGRAPHS] = run;
    }
}

__global__ void pool_sum2(const int* __restrict__ gstart, const float* __restrict__ h,
                          float* __restrict__ pooled) {
    int g = blockIdx.x, qtr = blockIdx.y;
    int b = gstart[g], e = gstart[g + 1];
    int cnt = e - b;
    int lo = b + (cnt * qtr) / 4, hi = b + (cnt * (qtr + 1)) / 4;
    if (lo >= hi) return;
    int c = threadIdx.x;
    float s = 0.f;
    for (int n = lo; n < hi; n++) s += h[(size_t)n * 256 + c];
    atomicAdd(&pooled[g * 256 + c], s);
}

__global__ void mlp_head(const float* __restrict__ pooled, const int* __restrict__ gcnt,
                         const float* __restrict__ fc1w, const float* __restrict__ fc1b,
                         const float* __restrict__ fc2w, const float* __restrict__ fc2b,
                         float* __restrict__ out) {
    int g = threadIdx.x;
    if (g >= NGRAPHS) return;
    float inv = 1.f / (float)(gcnt[g] > 0 ? gcnt[g] : 1);
    float s[64];
#pragma unroll
    for (int j = 0; j < 64; j++) s[j] = fc1b[j];
    for (int c = 0; c < 256; c++) {
        float mv = pooled[g * 256 + c] * inv;
#pragma unroll
        for (int j = 0; j < 64; j++) s[j] += mv * fc1w[c * 64 + j];
    }
    float o = 0.f;
#pragma unroll
    for (int j = 0; j < 64; j++) o += fmaxf(s[j], 0.f) * fc2w[j];
    out[g] = o + fc2b[0];
}

// ---------------- launch ----------------

extern "C" void kernel_launch(void* const* d_in, const int* in_sizes, int n_in,
                              void* d_out, int out_size, void* d_ws, size_t ws_size,
                              hipStream_t stream) {
    const float* x         = (const float*)d_in[0];
    const int*   edge_index= (const int*)d_in[1];
    const float* edge_attr = (const float*)d_in[2];
    const int*   batch     = (const int*)d_in[3];
    const int* src0 = edge_index;
    const int* dst0 = edge_index + N_EDGES;

    const float *Wl[4], *bl[4], *Wr[4], *br[4], *We[4], *att[4], *bias[4];
    for (int i = 0; i < 4; i++) {
        int base = 4 + 7 * i;
        Wl[i]   = (const float*)d_in[base + 0];
        bl[i]   = (const float*)d_in[base + 1];
        Wr[i]   = (const float*)d_in[base + 2];
        br[i]   = (const float*)d_in[base + 3];
        We[i]   = (const float*)d_in[base + 4];
        att[i]  = (const float*)d_in[base + 5];
        bias[i] = (const float*)d_in[base + 6];
    }
    const float* fc1w = (const float*)d_in[32];
    const float* fc1b = (const float*)d_in[33];
    const float* fc2w = (const float*)d_in[34];
    const float* fc2b = (const float*)d_in[35];
    float* out = (float*)d_out;

    // workspace layout (float offsets); footprint unchanged (ends 56493824)
    float* ws = (float*)d_ws;
    int*   rowptr  = (int*)(ws + 0);            // 8001
    int*   woff    = (int*)(ws + 8064);         // 8000
    int*   eid     = (int*)(ws + 16128);        // 72000
    int*   csr_src = (int*)(ws + 88128);        // 72000 -> ends 160128
    int*   csr_dst = (int*)(ws + 160128);       // 72000 -> ends 232128
    float* ea_loop = ws + 232128;               // 8000*16 -> ends 360128
    float* weT     = ws + 360128;               // 3328*16 = 53248 -> ends 413376
    float* ea_csr  = ws + 470000;               // 72000*16 = 1152000 -> ends 1622000
    int*   gstart  = (int*)(ws + 1700000);      // 65 ints (< 1728128)
    float* xlr     = ws + 1728128;              // 8000*3072 (xl | xr fused, stride 2hc)
    float* hbF     = xlr + 24576000;            // final-layer fp32 out (8000*256 used)
    float* pooled  = hbF + 12288000;            // 16384
    int*   gcnt    = (int*)(pooled + 16384);    // 64 -> pad to 38608640
    short* wth     = (short*)(ws + 38608640);   // max 2*1536*1024 shorts
    short* wtl     = (short*)(ws + 40181504);   // -> ends 41754368
    float* logits  = ws + 41754368;             // 72000*3 = 216000 -> ends 41970368
    short* acth    = (short*)(ws + 44107520);   // 8064*1536 shorts
    short* actl    = (short*)(ws + 50300672);   // -> ends 56493824

    hipMemsetAsync(woff, 0, N_NODES * sizeof(int), stream);
    count_deg<<<(N_EDGES + 255) / 256, 256, 0, stream>>>(dst0, woff);
    scan_deg2<<<1, 256, 0, stream>>>(woff, rowptr, woff);
    fill_eid<<<(ETOT + 255) / 256, 256, 0, stream>>>(dst0, woff, eid);
    csr_fill_dst<<<(N_NODES + 255) / 256, 256, 0, stream>>>(rowptr, csr_dst);
    ea_loop_kernel<<<(N_NODES + 255) / 256, 256, 0, stream>>>(rowptr, eid, edge_attr, ea_loop);
    csr_src_ea<<<(ETOT * 4 + 255) / 256, 256, 0, stream>>>(eid, src0, edge_attr, ea_loop,
                                                           csr_src, ea_csr);
    cvt_weT<<<(3328 + 255) / 256, 256, 0, stream>>>(We[0], We[1], We[2], We[3], weT);
    // layer-1 input split (later layers' splits come from aggregate5 epilogue)
    cvt_act<<<(N_NODES * 256 / 4 + 255) / 256, 256, 0, stream>>>(x, acth, actl, N_NODES * 256);

    const int IN[4] = {256, 1536, 1024, 512};
    const int HH[4] = {3, 2, 2, 1};
    const int CO[4] = {512, 512, 256, 256};
    const int CS[4] = {9, 9, 8, 8};            // log2(co)
    const int CHOFF[4] = {0, 1536, 2560, 3072}; // weT channel offsets

    for (int L = 0; L < 4; L++) {
        int K = IN[L], H = HH[L], co = CO[L], hc = H * co, cs = CS[L];
        int hc2 = 2 * hc;
        dim3 gg(hc2 / 128, (N_NODES + 127) / 128);
        dim3 gw(hc / 32, K / 32, 2);
        cvt_wt_t2<<<gw, 256, 0, stream>>>(Wl[L], Wr[L], wth, wtl, K, hc);
        gemm_mfma5<<<gg, 256, 0, stream>>>(acth, actl, wth, wtl,
                                           bl[L], br[L], hc, xlr, N_NODES, K, hc2);
        hipMemsetAsync(logits, 0, (size_t)ETOT * H * sizeof(float), stream);
        dim3 gl(ETOT / 64, hc >> 8);            // 256-channel slices
        edge_logits8<<<gl, 256, 0, stream>>>(
            csr_src, csr_dst, ea_csr, weT + (size_t)CHOFF[L] * 16,
            att[L], xlr, logits, H, cs, hc, hc2);
        int athr = hc / 4 > 256 ? 256 : hc / 4;
        aggregate5<<<N_NODES, athr, 0, stream>>>(
            rowptr, csr_src, logits, xlr, bias[L],
            acth, actl, hbF, (L == 3) ? 1 : 0, H, cs, hc, hc2);
    }

    hipMemsetAsync(pooled, 0, (16384 + 64) * sizeof(float), stream);
    pool_cnt<<<(N_NODES + 255) / 256, 256, 0, stream>>>(batch, gcnt);
    graph_scan<<<1, 64, 0, stream>>>(gcnt, gstart);
    dim3 gp(NGRAPHS, 4);
    pool_sum2<<<gp, 256, 0, stream>>>(gstart, hbF, pooled);
    mlp_head<<<1, 64, 0, stream>>>(pooled, gcnt, fc1w, fc1b, fc2w, fc2b, out);
}

// Round 8
// 1138.618 us; speedup vs baseline: 1.4661x; 1.0990x over previous
//
#include <hip/hip_runtime.h>
#include <math.h>

#define N_NODES 8000
#define N_EDGES 64000
#define ETOT    (N_EDGES + N_NODES)   // 72000, self-loops appended
#define EDIM    16
#define NGRAPHS 64

typedef __attribute__((ext_vector_type(8))) short short8v;
typedef __attribute__((ext_vector_type(4))) short short4v;
typedef __attribute__((ext_vector_type(4))) float f32x4;

__device__ inline unsigned short f2bf(float f) {
    unsigned u = __builtin_bit_cast(unsigned, f);
    unsigned r = (u + 0x7FFF + ((u >> 16) & 1)) >> 16;   // RNE
    return (unsigned short)r;
}
__device__ inline float bf2f(unsigned short b) {
    unsigned u = ((unsigned)b) << 16;
    return __builtin_bit_cast(float, u);
}

// direct global->LDS 16B DMA (dest = uniform base + lane*16)
__device__ inline void gload16(const void* g, void* l) {
    __builtin_amdgcn_global_load_lds(
        (const __attribute__((address_space(1))) void*)g,
        (__attribute__((address_space(3))) void*)l, 16, 0, 0);
}

// ---------------- CSR build ----------------

__global__ void count_deg(const int* __restrict__ dst0, int* __restrict__ deg) {
    int e = blockIdx.x * 256 + threadIdx.x;
    if (e < N_EDGES) atomicAdd(&deg[dst0[e]], 1);
}

// efficient single-block scan: 256 threads x 32 serial + one 256 block-scan.
// emits rowptr (inclusive, +self-loop) AND woff (exclusive) in one pass.
__global__ void scan_deg2(const int* __restrict__ deg, int* __restrict__ rowptr,
                          int* __restrict__ woff) {
    __shared__ int stot[256];
    int t = threadIdx.x;
    int base = t * 32;
    int sum = 0;
    for (int j = 0; j < 32; j++) {
        int i = base + j;
        if (i < N_NODES) sum += deg[i] + 1;
    }
    stot[t] = sum;
    __syncthreads();
    for (int off = 1; off < 256; off <<= 1) {
        int u = (t >= off) ? stot[t - off] : 0;
        __syncthreads();
        stot[t] += u;
        __syncthreads();
    }
    int run = (t == 0) ? 0 : stot[t - 1];
    if (t == 0) rowptr[0] = 0;
    for (int j = 0; j < 32; j++) {
        int i = base + j;
        if (i < N_NODES) {
            int v = deg[i] + 1;
            woff[i] = run;
            rowptr[i + 1] = run + v;
            run += v;
        }
    }
}

__global__ void fill_eid(const int* __restrict__ dst0, int* __restrict__ woff,
                         int* __restrict__ eid) {
    int i = blockIdx.x * 256 + threadIdx.x;
    if (i < N_EDGES) {
        int pos = atomicAdd(&woff[dst0[i]], 1);
        eid[pos] = i;
    } else if (i < ETOT) {
        int n = i - N_EDGES;
        int pos = atomicAdd(&woff[n], 1);
        eid[pos] = i;
    }
}

__global__ void csr_fill_dst(const int* __restrict__ rowptr, int* __restrict__ csr_dst) {
    int n = blockIdx.x * 256 + threadIdx.x;
    if (n >= N_NODES) return;
    int b = rowptr[n], t = rowptr[n + 1];
    for (int i = b; i < t; i++) csr_dst[i] = n;
}

__global__ void ea_loop_kernel(const int* __restrict__ rowptr, const int* __restrict__ eid,
                               const float* __restrict__ edge_attr, float* __restrict__ ea_loop) {
    int n = blockIdx.x * 256 + threadIdx.x;
    if (n >= N_NODES) return;
    float s[EDIM];
#pragma unroll
    for (int k = 0; k < EDIM; k++) s[k] = 0.f;
    int cnt = 0;
    int b = rowptr[n], t = rowptr[n + 1];
    for (int i = b; i < t; i++) {
        int e = eid[i];
        if (e < N_EDGES) {
            cnt++;
            const float* ea = edge_attr + (size_t)e * EDIM;
#pragma unroll
            for (int k = 0; k < EDIM; k++) s[k] += ea[k];
        }
    }
    float inv = 1.f / (float)(cnt > 0 ? cnt : 1);
#pragma unroll
    for (int k = 0; k < EDIM; k++) ea_loop[(size_t)n * EDIM + k] = s[k] * inv;
}

// csr_src + ea bf16 hi/lo split (MFMA B-layout [edge][32], k padded w/ zeros),
// fused: reads edge_attr/ea_loop via eid, emits eah/eal directly (no fp32 copy).
__global__ void csr_srcea_bf(const int* __restrict__ eid, const int* __restrict__ src0,
                             const float* __restrict__ edge_attr, const float* __restrict__ ea_loop,
                             int* __restrict__ csr_src,
                             short* __restrict__ eah, short* __restrict__ eal) {
    int t = blockIdx.x * 256 + threadIdx.x;
    int i = t >> 2, q = t & 3;
    if (i >= ETOT) return;
    int e = eid[i];
    int s = (e < N_EDGES) ? src0[e] : (e - N_EDGES);
    if (q == 0) csr_src[i] = s;
    const float* ea = (e < N_EDGES) ? edge_attr + (size_t)e * EDIM
                                    : ea_loop + (size_t)(e - N_EDGES) * EDIM;
    float4 v = *(const float4*)(ea + q * 4);
    unsigned short h0 = f2bf(v.x), h1 = f2bf(v.y), h2 = f2bf(v.z), h3 = f2bf(v.w);
    short4v hv = { (short)h0, (short)h1, (short)h2, (short)h3 };
    short4v lv = { (short)f2bf(v.x - bf2f(h0)), (short)f2bf(v.y - bf2f(h1)),
                   (short)f2bf(v.z - bf2f(h2)), (short)f2bf(v.w - bf2f(h3)) };
    short4v zv = { 0, 0, 0, 0 };
    *(short4v*)(eah + (size_t)i * 32 + q * 4) = hv;
    *(short4v*)(eal + (size_t)i * 32 + q * 4) = lv;
    *(short4v*)(eah + (size_t)i * 32 + 16 + q * 4) = zv;
    *(short4v*)(eal + (size_t)i * 32 + 16 + q * 4) = zv;
}

// All 4 layers' We -> WeT hi/lo [ch][32] in one launch (channel-flattened).
__global__ void cvt_we_all(const float* __restrict__ We1, const float* __restrict__ We2,
                           const float* __restrict__ We3, const float* __restrict__ We4,
                           short* __restrict__ weTh, short* __restrict__ weTl) {
    int ch = blockIdx.x * 256 + threadIdx.x;
    if (ch >= 3328) return;                  // 1536 + 1024 + 512 + 256
    const float* We; int lch, hc;
    if (ch < 1536)      { We = We1; lch = ch;        hc = 1536; }
    else if (ch < 2560) { We = We2; lch = ch - 1536; hc = 1024; }
    else if (ch < 3072) { We = We3; lch = ch - 2560; hc = 512;  }
    else                { We = We4; lch = ch - 3072; hc = 256;  }
#pragma unroll
    for (int k = 0; k < EDIM; k++) {
        float v = We[(size_t)k * hc + lch];
        unsigned short h = f2bf(v);
        unsigned short l = f2bf(v - bf2f(h));
        weTh[(size_t)ch * 32 + k] = (short)h;
        weTl[(size_t)ch * 32 + k] = (short)l;
    }
#pragma unroll
    for (int k = EDIM; k < 32; k++) {
        weTh[(size_t)ch * 32 + k] = 0;
        weTl[(size_t)ch * 32 + k] = 0;
    }
}

// ---------------- weight transpose + bf16 split, Wl & Wr in one launch (z) ----------------

__global__ __launch_bounds__(256) void cvt_wt_t2(
        const float* __restrict__ Wl, const float* __restrict__ Wr,
        short* __restrict__ WTh, short* __restrict__ WTl, int K, int Nc) {
    __shared__ float sh[32][33];
    const float* W = blockIdx.z ? Wr : Wl;
    size_t obase = blockIdx.z ? (size_t)Nc * K : 0;
    int t = threadIdx.x;
    int tx = t & 31, ty = t >> 5;            // 32 x 8
    int n0 = blockIdx.x * 32, k0 = blockIdx.y * 32;
#pragma unroll
    for (int j = 0; j < 4; j++)
        sh[ty + j * 8][tx] = W[(size_t)(k0 + ty + j * 8) * Nc + n0 + tx];
    __syncthreads();
#pragma unroll
    for (int j = 0; j < 4; j++) {
        int row = ty + j * 8;                 // local n
        float v = sh[tx][row];
        unsigned short h = f2bf(v);
        unsigned short l = f2bf(v - bf2f(h));
        size_t idx = obase + (size_t)(n0 + row) * K + k0 + tx;
        WTh[idx] = (short)h;
        WTl[idx] = (short)l;
    }
}

// ---------------- activation bf16 hi/lo pre-split (layer-1 input only) ----------------

__global__ __launch_bounds__(256) void cvt_act(
        const float* __restrict__ in, short* __restrict__ acth, short* __restrict__ actl,
        int total /* M*K, multiple of 4 */) {
    int i = blockIdx.x * 256 + threadIdx.x;
    if (i * 4 >= total) return;
    float4 v = *(const float4*)(in + (size_t)i * 4);
    unsigned short h0 = f2bf(v.x), h1 = f2bf(v.y), h2 = f2bf(v.z), h3 = f2bf(v.w);
    short4v hv = { (short)h0, (short)h1, (short)h2, (short)h3 };
    short4v lv = { (short)f2bf(v.x - bf2f(h0)), (short)f2bf(v.y - bf2f(h1)),
                   (short)f2bf(v.z - bf2f(h2)), (short)f2bf(v.w - bf2f(h3)) };
    *(short4v*)(acth + (size_t)i * 4) = hv;
    *(short4v*)(actl + (size_t)i * 4) = lv;
}

// ---------------- bf16x3 MFMA GEMM, A pre-split, fused Wl|Wr (dual bias) ----------------
// v5 (round-4 verified: FETCH 128MB = one-pass ideal, 0 bank conflicts,
// 175.6us L2-layer): single 32KB LDS buffer + T1 bijective XCD swizzle.
// Session-verified ceiling notes: dbuf+counted-vmcnt (v4) was NEUTRAL (m97
// structural ceiling, confirmed); reg-staged LDK=36 (v2) was 11% slower.

__global__ __launch_bounds__(256) void gemm_mfma5(
        const short* __restrict__ Ah_g, const short* __restrict__ Al_g,
        const short* __restrict__ BTh, const short* __restrict__ BTl,
        const float* __restrict__ bias1, const float* __restrict__ bias2, int hsplit,
        float* __restrict__ C, int M, int K, int Nc) {
    __shared__ __align__(16) short lds[4 * 128 * 32];   // Ah | Al | Bh | Bl, 32 KB
    int t = threadIdx.x;

    // T1: bijective XCD-chunked remap of the linear block id (m204).
    int gx = gridDim.x;
    int nwg = gx * gridDim.y;
    int orig = blockIdx.y * gx + blockIdx.x;
    int q = nwg >> 3, r = nwg & 7;
    int xcd = orig & 7, pos = orig >> 3;
    int nid = (xcd < r ? xcd * (q + 1) : r * (q + 1) + (xcd - r) * q) + pos;
    int bx = nid % gx, by = nid / gx;
    int m0 = by * 128, n0 = bx * 128;

    int lane = t & 63, wave = t >> 6;
    int wm = (wave >> 1) * 64, wn = (wave & 1) * 64;
    int fr = lane & 15, quad = lane >> 4;

    // staging: wave w owns matrix w; lane covers (row = g*16 + (lane>>2), seg = lane&3)
    int rl = lane >> 2, seg = lane & 3;
    int perm = seg ^ ((rl >> 1) & 3);                   // XOR involution
    const short* gp = (wave == 0) ? Ah_g : (wave == 1) ? Al_g : (wave == 2) ? BTh : BTl;
    int brow = (wave < 2) ? m0 : n0;
    const short* src = gp + (size_t)(brow + rl) * K + perm * 8;
    short* ldsw = &lds[wave * 4096];

    // read-side swizzled k-offset (shorts): (quad ^ ((fr>>1)&3)) * 8
    int ks = (quad ^ ((fr >> 1) & 3)) << 3;

    f32x4 acc[4][4];
#pragma unroll
    for (int i = 0; i < 4; i++)
#pragma unroll
        for (int j = 0; j < 4; j++) acc[i][j] = (f32x4)(0.f);

    for (int k0 = 0; k0 < K; k0 += 32) {
        __syncthreads();
#pragma unroll
        for (int g = 0; g < 8; g++)
            gload16(src + k0 + (size_t)g * 16 * K, ldsw + g * 512);
        __syncthreads();   // compiler drains vmcnt(0) before s_barrier

        short8v ah[4], al[4], bh[4], bl[4];
#pragma unroll
        for (int mi = 0; mi < 4; mi++) {
            int rr = (wm + mi * 16 + fr) * 32 + ks;
            ah[mi] = *(short8v*)&lds[rr];
            al[mi] = *(short8v*)&lds[4096 + rr];
        }
#pragma unroll
        for (int ni = 0; ni < 4; ni++) {
            int rr = (wn + ni * 16 + fr) * 32 + ks;
            bh[ni] = *(short8v*)&lds[8192 + rr];
            bl[ni] = *(short8v*)&lds[12288 + rr];
        }
#pragma unroll
        for (int mi = 0; mi < 4; mi++)
#pragma unroll
            for (int ni = 0; ni < 4; ni++) {
                acc[mi][ni] = __builtin_amdgcn_mfma_f32_16x16x32_bf16(
                    al[mi], bh[ni], acc[mi][ni], 0, 0, 0);
                acc[mi][ni] = __builtin_amdgcn_mfma_f32_16x16x32_bf16(
                    ah[mi], bl[ni], acc[mi][ni], 0, 0, 0);
                acc[mi][ni] = __builtin_amdgcn_mfma_f32_16x16x32_bf16(
                    ah[mi], bh[ni], acc[mi][ni], 0, 0, 0);
            }
    }

    int rbase = (lane >> 4) * 4;
#pragma unroll
    for (int ni = 0; ni < 4; ni++) {
        int col = n0 + wn + ni * 16 + fr;
        const float* bp = (col < hsplit) ? bias1 + col : bias2 + (col - hsplit);
        float bz = *bp;
#pragma unroll
        for (int mi = 0; mi < 4; mi++) {
            int row0 = m0 + wm + mi * 16 + rbase;
#pragma unroll
            for (int rr = 0; rr < 4; rr++) {
                int row = row0 + rr;
                if (row < M) C[(size_t)row * Nc + col] = acc[mi][ni][rr] + bz;
            }
        }
    }
}

// ---------------- edge logits v7: MFMA ee, per-head block, 2-deep pipeline ----------------
// Session-verified best pass-1 (R7's coalesced wave-per-edge v8 was SLOWER:
// 204us L1 vs <175 here — v8 traded memory-level parallelism for coalescing
// and became L3-latency-bound). This layout keeps 64 scattered 16B requests
// in flight per wave instruction.

__global__ __launch_bounds__(256, 4) void edge_logits7(
        const float* __restrict__ xl, const float* __restrict__ xr,
        const short* __restrict__ weTh, const short* __restrict__ weTl,
        const float* __restrict__ att,
        const short* __restrict__ eah, const short* __restrict__ eal,
        const int* __restrict__ csr_src, const int* __restrict__ csr_dst,
        float* __restrict__ logits, int H, int co, int stride) {
    int tid = threadIdx.x;
    int lane = tid & 63, wave = tid >> 6;
    int head = blockIdx.y;
    int cbase = head * co;
    int e0 = blockIdx.x * 64 + wave * 16;    // ETOT % 64 == 0
    int col = lane & 15;                     // edge within tile
    int quad = lane >> 4;
    int e = e0 + col;
    int s = csr_src[e], d = csr_dst[e];
    int ch0 = cbase + quad * 4;

    short8v bh = *(const short8v*)(eah + (size_t)e * 32 + quad * 8);
    short8v bl = *(const short8v*)(eal + (size_t)e * 32 + quad * 8);

    const float* xls = xl + (size_t)s * stride + ch0;
    const float* xrd = xr + (size_t)d * stride + ch0;
    const float* atp = att + ch0;
    const short* wph = weTh + (size_t)(cbase + col) * 32 + quad * 8;
    const short* wpl = weTl + (size_t)(cbase + col) * 32 + quad * 8;

    int ntile = co >> 4;
    float p = 0.f;

    short8v ahA = *(const short8v*)wph;
    short8v alA = *(const short8v*)wpl;
    float4 lvA = *(const float4*)xls;
    float4 rvA = *(const float4*)xrd;
    float4 avA = *(const float4*)atp;

    for (int tt = 0; tt < ntile - 1; tt++) {
        short8v ahB = *(const short8v*)(wph + (size_t)(tt + 1) * 512);
        short8v alB = *(const short8v*)(wpl + (size_t)(tt + 1) * 512);
        float4 lvB = *(const float4*)(xls + (tt + 1) * 16);
        float4 rvB = *(const float4*)(xrd + (tt + 1) * 16);
        float4 avB = *(const float4*)(atp + (tt + 1) * 16);

        f32x4 ee = (f32x4)(0.f);
        ee = __builtin_amdgcn_mfma_f32_16x16x32_bf16(ahA, bl, ee, 0, 0, 0);
        ee = __builtin_amdgcn_mfma_f32_16x16x32_bf16(alA, bh, ee, 0, 0, 0);
        ee = __builtin_amdgcn_mfma_f32_16x16x32_bf16(ahA, bh, ee, 0, 0, 0);
        float m0 = lvA.x + rvA.x + ee[0];
        float m1 = lvA.y + rvA.y + ee[1];
        float m2 = lvA.z + rvA.z + ee[2];
        float m3 = lvA.w + rvA.w + ee[3];
        m0 = (m0 > 0.f) ? m0 : 0.2f * m0;
        m1 = (m1 > 0.f) ? m1 : 0.2f * m1;
        m2 = (m2 > 0.f) ? m2 : 0.2f * m2;
        m3 = (m3 > 0.f) ? m3 : 0.2f * m3;
        p += m0 * avA.x + m1 * avA.y + m2 * avA.z + m3 * avA.w;

        ahA = ahB; alA = alB; lvA = lvB; rvA = rvB; avA = avB;
    }
    {
        f32x4 ee = (f32x4)(0.f);
        ee = __builtin_amdgcn_mfma_f32_16x16x32_bf16(ahA, bl, ee, 0, 0, 0);
        ee = __builtin_amdgcn_mfma_f32_16x16x32_bf16(alA, bh, ee, 0, 0, 0);
        ee = __builtin_amdgcn_mfma_f32_16x16x32_bf16(ahA, bh, ee, 0, 0, 0);
        float m0 = lvA.x + rvA.x + ee[0];
        float m1 = lvA.y + rvA.y + ee[1];
        float m2 = lvA.z + rvA.z + ee[2];
        float m3 = lvA.w + rvA.w + ee[3];
        m0 = (m0 > 0.f) ? m0 : 0.2f * m0;
        m1 = (m1 > 0.f) ? m1 : 0.2f * m1;
        m2 = (m2 > 0.f) ? m2 : 0.2f * m2;
        m3 = (m3 > 0.f) ? m3 : 0.2f * m3;
        p += m0 * avA.x + m1 * avA.y + m2 * avA.z + m3 * avA.w;
    }

    p += __shfl_down(p, 32, 64);
    p += __shfl_down(p, 16, 64);
    if (lane < 16)
        logits[(size_t)(e0 + lane) * H + head] = p;
}

// ---------------- fused softmax + aggregation v5: bf16 hi/lo epilogue ----------------

__global__ __launch_bounds__(256) void aggregate5(
        const int* __restrict__ rowptr, const int* __restrict__ csr_src,
        const float* __restrict__ logits, const float* __restrict__ xl,
        const float* __restrict__ bias,
        short* __restrict__ outh, short* __restrict__ outl,
        float* __restrict__ outf, int last,
        int H, int co_shift, int hc, int stride) {
    __shared__ int ssrc[64];
    __shared__ float salp[64][4];
    __shared__ float sm[4], sinv[4];
    int n = blockIdx.x;
    int b = rowptr[n], t = rowptr[n + 1];
    int tid = threadIdx.x;
    int nthr = blockDim.x;

    if (tid < H) {
        float m = -1e30f;
        for (int i = b; i < t; i++)
            m = fmaxf(m, logits[(size_t)i * H + tid]);
        float s = 0.f;
        for (int i = b; i < t; i++)
            s += expf(logits[(size_t)i * H + tid] - m);
        sm[tid] = m;
        sinv[tid] = 1.f / s;    // self-loop guarantees s > 0
    }
    __syncthreads();

    int j0 = tid * 4;
    int j1 = j0 + nthr * 4;
    int h0 = j0 >> co_shift;
    int h1 = j1 >> co_shift;
    bool act1 = j1 < hc;

    float4 acc0 = make_float4(0.f, 0.f, 0.f, 0.f);
    float4 acc1 = make_float4(0.f, 0.f, 0.f, 0.f);

    for (int cb = b; cb < t; cb += 64) {
        int m = min(64, t - cb);
        __syncthreads();
        for (int i = tid; i < m; i += nthr) {
            ssrc[i] = csr_src[cb + i];
            for (int h = 0; h < H; h++)
                salp[i][h] = expf(logits[(size_t)(cb + i) * H + h] - sm[h]) * sinv[h];
        }
        __syncthreads();
        for (int i = 0; i < m; i++) {
            int s = ssrc[i];
            const float* base = xl + (size_t)s * stride;
            {
                float a = salp[i][h0];
                float4 v = *(const float4*)(base + j0);
                acc0.x += a * v.x; acc0.y += a * v.y;
                acc0.z += a * v.z; acc0.w += a * v.w;
            }
            if (act1) {
                float a = salp[i][h1];
                float4 v = *(const float4*)(base + j1);
                acc1.x += a * v.x; acc1.y += a * v.y;
                acc1.z += a * v.z; acc1.w += a * v.w;
            }
        }
    }

    float4 bz0 = *(const float4*)(bias + j0);
    float4 o0;
    o0.x = fmaxf(acc0.x + bz0.x, 0.f); o0.y = fmaxf(acc0.y + bz0.y, 0.f);
    o0.z = fmaxf(acc0.z + bz0.z, 0.f); o0.w = fmaxf(acc0.w + bz0.w, 0.f);
    if (last) {
        *(float4*)(outf + (size_t)n * hc + j0) = o0;
    } else {
        unsigned short hx = f2bf(o0.x), hy = f2bf(o0.y), hz = f2bf(o0.z), hw = f2bf(o0.w);
        short4v hv = { (short)hx, (short)hy, (short)hz, (short)hw };
        short4v lv = { (short)f2bf(o0.x - bf2f(hx)), (short)f2bf(o0.y - bf2f(hy)),
                       (short)f2bf(o0.z - bf2f(hz)), (short)f2bf(o0.w - bf2f(hw)) };
        *(short4v*)(outh + (size_t)n * hc + j0) = hv;
        *(short4v*)(outl + (size_t)n * hc + j0) = lv;
    }
    if (act1) {
        float4 bz1 = *(const float4*)(bias + j1);
        float4 o1;
        o1.x = fmaxf(acc1.x + bz1.x, 0.f); o1.y = fmaxf(acc1.y + bz1.y, 0.f);
        o1.z = fmaxf(acc1.z + bz1.z, 0.f); o1.w = fmaxf(acc1.w + bz1.w, 0.f);
        if (last) {
            *(float4*)(outf + (size_t)n * hc + j1) = o1;
        } else {
            unsigned short hx = f2bf(o1.x), hy = f2bf(o1.y), hz = f2bf(o1.z), hw = f2bf(o1.w);
            short4v hv = { (short)hx, (short)hy, (short)hz, (short)hw };
            short4v lv = { (short)f2bf(o1.x - bf2f(hx)), (short)f2bf(o1.y - bf2f(hy)),
                           (short)f2bf(o1.z - bf2f(hz)), (short)f2bf(o1.w - bf2f(hw)) };
            *(short4v*)(outh + (size_t)n * hc + j1) = hv;
            *(short4v*)(outl + (size_t)n * hc + j1) = lv;
        }
    }
}

// ---------------- pooling + MLP head ----------------
// batch is sorted -> per-graph node ranges; pool_sum2 does coalesced row sums
// with 65K spread atomics (vs 2M contended in the original pool_sum).

__global__ void pool_cnt(const int* __restrict__ batch, int* __restrict__ gcnt) {
    int n = blockIdx.x * 256 + threadIdx.x;
    if (n < N_NODES) atomicAdd(&gcnt[batch[n]], 1);
}

__global__ void graph_scan(const int* __restrict__ gcnt, int* __restrict__ gstart) {
    if (threadIdx.x == 0) {
        int run = 0;
        for (int g = 0; g < NGRAPHS; g++) { gstart[g] = run; run += gcnt[g]; }
        gstart[NGRAPHS] = run;
    }
}

__global__ void pool_sum2(const int* __restrict__ gstart, const float* __restrict__ h,
                          float* __restrict__ pooled) {
    int g = blockIdx.x, qtr = blockIdx.y;
    int b = gstart[g], e = gstart[g + 1];
    int cnt = e - b;
    int lo = b + (cnt * qtr) / 4, hi = b + (cnt * (qtr + 1)) / 4;
    if (lo >= hi) return;
    int c = threadIdx.x;
    float s = 0.f;
    for (int n = lo; n < hi; n++) s += h[(size_t)n * 256 + c];
    atomicAdd(&pooled[g * 256 + c], s);
}

__global__ void mlp_head(const float* __restrict__ pooled, const int* __restrict__ gcnt,
                         const float* __restrict__ fc1w, const float* __restrict__ fc1b,
                         const float* __restrict__ fc2w, const float* __restrict__ fc2b,
                         float* __restrict__ out) {
    int g = threadIdx.x;
    if (g >= NGRAPHS) return;
    float inv = 1.f / (float)(gcnt[g] > 0 ? gcnt[g] : 1);
    float s[64];
#pragma unroll
    for (int j = 0; j < 64; j++) s[j] = fc1b[j];
    for (int c = 0; c < 256; c++) {
        float mv = pooled[g * 256 + c] * inv;
#pragma unroll
        for (int j = 0; j < 64; j++) s[j] += mv * fc1w[c * 64 + j];
    }
    float o = 0.f;
#pragma unroll
    for (int j = 0; j < 64; j++) o += fmaxf(s[j], 0.f) * fc2w[j];
    out[g] = o + fc2b[0];
}

// ---------------- launch ----------------

extern "C" void kernel_launch(void* const* d_in, const int* in_sizes, int n_in,
                              void* d_out, int out_size, void* d_ws, size_t ws_size,
                              hipStream_t stream) {
    const float* x         = (const float*)d_in[0];
    const int*   edge_index= (const int*)d_in[1];
    const float* edge_attr = (const float*)d_in[2];
    const int*   batch     = (const int*)d_in[3];
    const int* src0 = edge_index;
    const int* dst0 = edge_index + N_EDGES;

    const float *Wl[4], *bl[4], *Wr[4], *br[4], *We[4], *att[4], *bias[4];
    for (int i = 0; i < 4; i++) {
        int base = 4 + 7 * i;
        Wl[i]   = (const float*)d_in[base + 0];
        bl[i]   = (const float*)d_in[base + 1];
        Wr[i]   = (const float*)d_in[base + 2];
        br[i]   = (const float*)d_in[base + 3];
        We[i]   = (const float*)d_in[base + 4];
        att[i]  = (const float*)d_in[base + 5];
        bias[i] = (const float*)d_in[base + 6];
    }
    const float* fc1w = (const float*)d_in[32];
    const float* fc1b = (const float*)d_in[33];
    const float* fc2w = (const float*)d_in[34];
    const float* fc2b = (const float*)d_in[35];
    float* out = (float*)d_out;

    // workspace layout (float offsets); end unchanged at 56493824 floats (~226 MB, verified)
    float* ws = (float*)d_ws;
    int*   rowptr  = (int*)(ws + 0);            // 8001
    int*   woff    = (int*)(ws + 8064);         // 8000
    int*   eid     = (int*)(ws + 16128);        // 72000
    int*   csr_src = (int*)(ws + 88128);        // 72000
    int*   csr_dst = (int*)(ws + 160128);       // 72000
    float* ea_loop = ws + 232128;               // 8000*16 -> ends 360128
    short* weTh_a  = (short*)(ws + 360128);     // 3328*32 shorts = 53248 floats
    short* weTl_a  = (short*)(ws + 413376);     // -> ends 466624
    int*   gstart  = (int*)(ws + 470000);       // 65 ints (hole until 1512128)
    float* logits  = ws + 1512128;              // 72000*3
    float* xlr     = ws + 1728128;              // 8000*3072 (xl | xr fused, stride 2hc)
    float* hbF     = xlr + 24576000;            // final-layer fp32 out (8000*256 used)
    float* pooled  = hbF + 12288000;            // 16384
    int*   gcnt    = (int*)(pooled + 16384);    // 64 -> pad to 38608640
    short* wth     = (short*)(ws + 38608640);   // max 2*1536*1024 shorts = 1572864 floats
    short* wtl     = (short*)(ws + 40181504);   // -> ends 41754368
    short* eah     = (short*)(ws + 41754368);   // 72000*32 shorts = 1152000 floats
    short* eal     = (short*)(ws + 42906368);   // -> ends 44058368
    short* acth    = (short*)(ws + 44107520);   // 8064*1536 shorts = 6193152 floats
    short* actl    = (short*)(ws + 50300672);   // -> ends 56493824

    hipMemsetAsync(woff, 0, N_NODES * sizeof(int), stream);
    count_deg<<<(N_EDGES + 255) / 256, 256, 0, stream>>>(dst0, woff);
    scan_deg2<<<1, 256, 0, stream>>>(woff, rowptr, woff);
    fill_eid<<<(ETOT + 255) / 256, 256, 0, stream>>>(dst0, woff, eid);
    csr_fill_dst<<<(N_NODES + 255) / 256, 256, 0, stream>>>(rowptr, csr_dst);
    ea_loop_kernel<<<(N_NODES + 255) / 256, 256, 0, stream>>>(rowptr, eid, edge_attr, ea_loop);
    csr_srcea_bf<<<(ETOT * 4 + 255) / 256, 256, 0, stream>>>(eid, src0, edge_attr, ea_loop,
                                                             csr_src, eah, eal);
    cvt_we_all<<<(3328 + 255) / 256, 256, 0, stream>>>(We[0], We[1], We[2], We[3],
                                                       weTh_a, weTl_a);
    // layer-1 input split (later layers' splits come from aggregate5 epilogue)
    cvt_act<<<(N_NODES * 256 / 4 + 255) / 256, 256, 0, stream>>>(x, acth, actl, N_NODES * 256);

    const int IN[4] = {256, 1536, 1024, 512};
    const int HH[4] = {3, 2, 2, 1};
    const int CO[4] = {512, 512, 256, 256};
    const int CS[4] = {9, 9, 8, 8};            // log2(co)
    const int CHOFF[4] = {0, 1536, 2560, 3072}; // weT channel offsets

    for (int L = 0; L < 4; L++) {
        int K = IN[L], H = HH[L], co = CO[L], hc = H * co, cs = CS[L];
        int hc2 = 2 * hc;
        dim3 gg(hc2 / 128, (N_NODES + 127) / 128);
        dim3 gw(hc / 32, K / 32, 2);
        cvt_wt_t2<<<gw, 256, 0, stream>>>(Wl[L], Wr[L], wth, wtl, K, hc);
        gemm_mfma5<<<gg, 256, 0, stream>>>(acth, actl, wth, wtl,
                                           bl[L], br[L], hc, xlr, N_NODES, K, hc2);
        dim3 gl(ETOT / 64, H);
        edge_logits7<<<gl, 256, 0, stream>>>(
            xlr, xlr + hc,
            weTh_a + (size_t)CHOFF[L] * 32, weTl_a + (size_t)CHOFF[L] * 32,
            att[L], eah, eal, csr_src, csr_dst, logits, H, co, hc2);
        int athr = hc / 4 > 256 ? 256 : hc / 4;
        aggregate5<<<N_NODES, athr, 0, stream>>>(
            rowptr, csr_src, logits, xlr, bias[L],
            acth, actl, hbF, (L == 3) ? 1 : 0, H, cs, hc, hc2);
    }

    hipMemsetAsync(pooled, 0, (16384 + 64) * sizeof(float), stream);
    pool_cnt<<<(N_NODES + 255) / 256, 256, 0, stream>>>(batch, gcnt);
    graph_scan<<<1, 64, 0, stream>>>(gcnt, gstart);
    dim3 gp(NGRAPHS, 4);
    pool_sum2<<<gp, 256, 0, stream>>>(gstart, hbF, pooled);
    mlp_head<<<1, 64, 0, stream>>>(pooled, gcnt, fc1w, fc1b, fc2w, fc2b, out);
}